// Round 13
// baseline (420.836 us; speedup 1.0000x reference)
//
#include <hip/hip_runtime.h>
#include <cstdint>
#include <math.h>

typedef unsigned int u32;
typedef unsigned long long u64;
typedef unsigned short ushort;

typedef __attribute__((ext_vector_type(8))) _Float16 f16x8;
typedef __attribute__((ext_vector_type(4))) _Float16 f16x4;
typedef __attribute__((ext_vector_type(4))) float f32x4;

#define NB    4
#define BnN   2048
#define NE    261632      // 512*511 ordered pairs per batch
#define NCHUNK 16
#define ECHUNK 16352      // NE/16
#define KEDGE 4096
#define TIECAP 2048
#define PSLICE 2359296    // 4*2304*256 elements per K-slice partial
#define MS    64          // meta stride (u32) per sel -> 256B, own cache lines
#define TS    64          // tiecnt stride (int) per sel

// meta[sel*MS+i]: 0:p12  1:need1  2:qlo  3:qhi  4:wstar  5:emitcnt  6:prefix24  7:need2
// ---------------------------------------------------------------------------
// convert input: NCHW fp32 -> NHWC f16.  grid (16 chgrp, 48 y, 4 b), block 256
// ---------------------------------------------------------------------------
__global__ __launch_bounds__(256) void cvt_x_kernel(
    const float* __restrict__ in, _Float16* __restrict__ xf)
{
    __shared__ _Float16 sh[64][49];
    int cg = blockIdx.x, y = blockIdx.y, b = blockIdx.z;
    int tid = threadIdx.x;
    for (int i = tid; i < 64 * 48; i += 256) {
        int cl = i / 48, x = i - cl * 48;
        sh[cl][x] = (_Float16)in[(((size_t)b * 1024 + cg * 64 + cl) * 48 + y) * 48 + x];
    }
    __syncthreads();
    for (int i = tid; i < 64 * 48; i += 256) {
        int x = i / 64, cl = i - x * 64;
        xf[((size_t)(b * 48 + y) * 48 + x) * 1024 + cg * 64 + cl] = sh[cl][x];
    }
}

// convert weights: [o][ch][3][3] fp32 -> [o][tap][ch] f16. grid 256, block 256
__global__ __launch_bounds__(256) void cvt_w_kernel(
    const float* __restrict__ W, _Float16* __restrict__ wf)
{
    __shared__ _Float16 sh[9216];
    int o = blockIdx.x, tid = threadIdx.x;
    for (int g = tid; g < 9216; g += 256)
        sh[g] = (_Float16)W[(size_t)o * 9216 + g];     // g = ch*9+tap
    __syncthreads();
    for (int g = tid; g < 9216; g += 256) {
        int tap = g >> 10, ch = g & 1023;
        wf[(size_t)o * 9216 + g] = sh[ch * 9 + tap];
    }
}

// transpose-convert: in fp32 [K][N] -> out f16 [N][K]. grid (ceil(N/32), ceil(K/32))
__global__ __launch_bounds__(256) void cvt_t_kernel(
    const float* __restrict__ in, _Float16* __restrict__ out, int K, int N)
{
    __shared__ _Float16 sh[32][33];
    int n0 = blockIdx.x * 32, k0 = blockIdx.y * 32;
    int tx = threadIdx.x & 31, ty = threadIdx.x >> 5;
#pragma unroll
    for (int i = 0; i < 4; ++i) {
        int k = k0 + ty + i * 8, n = n0 + tx;
        sh[ty + i * 8][tx] = (k < K && n < N) ? (_Float16)in[(size_t)k * N + n] : (_Float16)0.f;
    }
    __syncthreads();
#pragma unroll
    for (int i = 0; i < 4; ++i) {
        int n = n0 + ty + i * 8, k = k0 + tx;
        if (n < N && k < K) out[(size_t)n * K + k] = sh[tx][ty + i * 8];
    }
}

// ---------------------------------------------------------------------------
// conv 3x3 SAME 1024->256, split-K(4) partials. Implicit-GEMM MFMA f16.
// Block 256 thr (4 waves). Wave tile: 64 och x 2 rows x 48 px.
// K-loop software-pipelined via register prefetch: next chunk's 17 dwordx4
// loads are issued right after the LDS-write barrier, so global latency
// overlaps the 216-MFMA compute (2-barrier structure kept).
// grid (6 ygroup[8 rows], 4 og[64 och], 16 = b*4+kslice). K = 256 ch/block.
// ---------------------------------------------------------------------------
__global__ __launch_bounds__(256) void conv_part_kernel(
    const _Float16* __restrict__ xf, const _Float16* __restrict__ wf,
    float* __restrict__ pbuf)
{
    __shared__ _Float16 wS[9][4][64][8];   // 36.9 KB  [tap][q][och64][8ch]
    __shared__ _Float16 xS[10][4][50][8];  // 32.0 KB  [row10][q][col][8ch]
    const int y0 = blockIdx.x * 8;
    const int og = blockIdx.y;
    const int bz = blockIdx.z;
    const int b  = bz >> 2, ks = bz & 3;
    const int tid = threadIdx.x;
    const int wv = tid >> 6;
    const int ln = tid & 63;
    const int n  = ln & 15;
    const int q  = ln >> 4;

    // ---- precompute per-it source bases and LDS destinations ----
    const _Float16* wsrc[9];
    uint4* wdst[9];
#pragma unroll
    for (int it = 0; it < 9; ++it) {
        int g = it * 256 + tid;
        int tap = g >> 8, r = g & 255, qq = r >> 6, oc = r & 63;
        wsrc[it] = wf + ((size_t)(og * 64 + oc) * 9 + tap) * 1024 + qq * 8;
        wdst[it] = (uint4*)&wS[tap][qq][oc][0];
    }
    const _Float16* xsrc[8];
    uint4* xdst[8];
    bool xok[8];
#pragma unroll
    for (int it = 0; it < 8; ++it) {
        int g = it * 256 + tid;
        int row = g / 200, r2 = g - row * 200;
        int qq = r2 / 50, c = r2 - qq * 50;
        int gy = y0 + row - 1, gx = c - 1;
        bool valid = (g < 2000) && ((unsigned)gy < 48u) && ((unsigned)gx < 48u);
        xok[it] = valid;
        xsrc[it] = valid ? (xf + ((size_t)(b * 48 + gy) * 48 + gx) * 1024 + qq * 8) : xf;
        xdst[it] = (g < 2000) ? (uint4*)&xS[row][qq][c][0] : (uint4*)&xS[0][0][0][0];
        if (!(g < 2000)) xdst[it] = nullptr;
    }

    f32x4 acc[4][2][3];
#pragma unroll
    for (int mt = 0; mt < 4; ++mt)
#pragma unroll
        for (int rr = 0; rr < 2; ++rr)
#pragma unroll
            for (int nt = 0; nt < 3; ++nt) acc[mt][rr][nt] = (f32x4){0.f, 0.f, 0.f, 0.f};

    const int c0 = ks * 256;
    uint4 wreg[9], xreg[8];

    // prologue: load chunk 0
#pragma unroll
    for (int it = 0; it < 9; ++it) wreg[it] = *(const uint4*)(wsrc[it] + c0);
#pragma unroll
    for (int it = 0; it < 8; ++it)
        xreg[it] = xok[it] ? *(const uint4*)(xsrc[it] + c0) : make_uint4(0u, 0u, 0u, 0u);

    for (int ci = 0; ci < 8; ++ci) {
        const int ccn = c0 + (ci + 1) * 32;
        // write current regs to LDS
#pragma unroll
        for (int it = 0; it < 9; ++it) *wdst[it] = wreg[it];
#pragma unroll
        for (int it = 0; it < 8; ++it) if (xdst[it]) *xdst[it] = xreg[it];
        __syncthreads();
        // prefetch next chunk (loads overlap the MFMA compute below)
        if (ci < 7) {
#pragma unroll
            for (int it = 0; it < 9; ++it) wreg[it] = *(const uint4*)(wsrc[it] + ccn);
#pragma unroll
            for (int it = 0; it < 8; ++it)
                xreg[it] = xok[it] ? *(const uint4*)(xsrc[it] + ccn) : make_uint4(0u, 0u, 0u, 0u);
        }

#pragma unroll
        for (int tap = 0; tap < 9; ++tap) {
            const int dy = tap / 3, dx = tap % 3;
            f16x8 a[4];
#pragma unroll
            for (int mt = 0; mt < 4; ++mt)
                a[mt] = *(const f16x8*)&wS[tap][q][mt * 16 + n][0];
#pragma unroll
            for (int rr = 0; rr < 2; ++rr) {
                const int row = 2 * wv + rr + dy;
#pragma unroll
                for (int nt = 0; nt < 3; ++nt) {
                    f16x8 bb = *(const f16x8*)&xS[row][q][nt * 16 + n + dx][0];
#pragma unroll
                    for (int mt = 0; mt < 4; ++mt)
                        acc[mt][rr][nt] = __builtin_amdgcn_mfma_f32_16x16x32_f16(a[mt], bb, acc[mt][rr][nt], 0, 0, 0);
                }
            }
        }
        __syncthreads();
    }

    // epilogue: px = nt*16+n, och = og*64 + mt*16 + q*4 + reg, y = y0+2wv+rr
#pragma unroll
    for (int rr = 0; rr < 2; ++rr) {
        const int y = y0 + 2 * wv + rr;
#pragma unroll
        for (int mt = 0; mt < 4; ++mt) {
#pragma unroll
            for (int nt = 0; nt < 3; ++nt) {
                int x = nt * 16 + n;
                *(f32x4*)(pbuf + (size_t)ks * PSLICE +
                          ((size_t)(b * 48 + y) * 48 + x) * 256 + og * 64 + mt * 16 + q * 4) = acc[mt][rr][nt];
            }
        }
    }
}

// sum 4 partials + bias + relu -> dec NHWC f16. grid 2304 x 256.
__global__ __launch_bounds__(256) void conv_sum_kernel(
    const float* __restrict__ pbuf, const float* __restrict__ bd,
    _Float16* __restrict__ dec)
{
    size_t idx = (size_t)blockIdx.x * 256 + threadIdx.x;   // 589824 threads
    size_t e = idx * 4;
    int och = (int)(e & 255);
    f32x4 s0 = *(const f32x4*)(pbuf + e);
    f32x4 s1 = *(const f32x4*)(pbuf + (size_t)PSLICE + e);
    f32x4 s2 = *(const f32x4*)(pbuf + (size_t)2 * PSLICE + e);
    f32x4 s3 = *(const f32x4*)(pbuf + (size_t)3 * PSLICE + e);
    float4 b4 = *(const float4*)(bd + och);
    f16x4 v;
    v.x = (_Float16)fmaxf(s0[0] + s1[0] + s2[0] + s3[0] + b4.x, 0.f);
    v.y = (_Float16)fmaxf(s0[1] + s1[1] + s2[1] + s3[1] + b4.y, 0.f);
    v.z = (_Float16)fmaxf(s0[2] + s1[2] + s2[2] + s3[2] + b4.z, 0.f);
    v.w = (_Float16)fmaxf(s0[3] + s1[3] + s2[3] + s3[3] + b4.w, 0.f);
    *(f16x4*)(dec + e) = v;
}

// ---------------------------------------------------------------------------
// ROI align 2x2 on NHWC f16 dec
// ---------------------------------------------------------------------------
__global__ __launch_bounds__(256) void roi_kernel(
    const _Float16* __restrict__ dec, const float* __restrict__ boxes,
    _Float16* __restrict__ cnn)
{
    int n = blockIdx.x; int c = threadIdx.x;
    int b = n >> 9;
    float x1 = boxes[n * 4 + 0], y1 = boxes[n * 4 + 1];
    float x2 = boxes[n * 4 + 2], y2 = boxes[n * 4 + 3];
    float bw = (x2 - x1) * 0.5f, bh = (y2 - y1) * 0.5f;
    float sxv[2] = { x1 + 0.5f * bw, x1 + 1.5f * bw };
    float syv[2] = { y1 + 0.5f * bh, y1 + 1.5f * bh };
    float px[4] = { sxv[0], sxv[1], sxv[0], sxv[1] };
    float py[4] = { syv[0], syv[0], syv[1], syv[1] };
    const _Float16* f = dec + (size_t)b * 2304 * 256;
    f16x4 o4;
    float res[4];
#pragma unroll
    for (int p = 0; p < 4; ++p) {
        float yy = fminf(fmaxf(py[p], 0.f), 47.f);
        float xx = fminf(fmaxf(px[p], 0.f), 47.f);
        int y0 = (int)floorf(yy), x0 = (int)floorf(xx);
        int y1i = min(y0 + 1, 47), x1i = min(x0 + 1, 47);
        float wy = yy - (float)y0, wx = xx - (float)x0;
        float f00 = (float)f[(size_t)(y0 * 48 + x0) * 256 + c];
        float f01 = (float)f[(size_t)(y0 * 48 + x1i) * 256 + c];
        float f10 = (float)f[(size_t)(y1i * 48 + x0) * 256 + c];
        float f11 = (float)f[(size_t)(y1i * 48 + x1i) * 256 + c];
        res[p] = f00 * (1.f - wy) * (1.f - wx) + f01 * (1.f - wy) * wx
               + f10 * wy * (1.f - wx) + f11 * wy * wx;
    }
    o4.x = (_Float16)res[0]; o4.y = (_Float16)res[1];
    o4.z = (_Float16)res[2]; o4.w = (_Float16)res[3];
    *(f16x4*)(cnn + (size_t)n * 1024 + c * 4) = o4;
}

// ---------------------------------------------------------------------------
// box head: fusion[:, 0:256] = relu(bf @ W_box + b_box)
// ---------------------------------------------------------------------------
__global__ __launch_bounds__(256) void box_kernel(
    const float* __restrict__ boxes, const float* __restrict__ Wb,
    const float* __restrict__ bb, _Float16* __restrict__ fusion)
{
    int nrow = blockIdx.x, c = threadIdx.x;
    float x1 = boxes[nrow * 4 + 0], y1 = boxes[nrow * 4 + 1];
    float x2 = boxes[nrow * 4 + 2], y2 = boxes[nrow * 4 + 3];
    float bf0 = ((x1 + x2) * 0.5f) / 48.f;
    float bf1 = ((y1 + y2) * 0.5f) / 48.f;
    float bf2 = (x2 - x1) / 48.f;
    float bf3 = (y2 - y1) / 48.f;
    float acc = bb[c];
    acc += bf0 * Wb[0 * 256 + c];
    acc += bf1 * Wb[1 * 256 + c];
    acc += bf2 * Wb[2 * 256 + c];
    acc += bf3 * Wb[3 * 256 + c];
    fusion[(size_t)nrow * 768 + c] = (_Float16)fmaxf(acc, 0.f);
}

// ---------------------------------------------------------------------------
// f16 MFMA GEMM: C = act(A @ Bt^T + bias). 64x64 tile, 4 waves 2x2.
// ---------------------------------------------------------------------------
template <int ACT, typename OUTT>
__global__ __launch_bounds__(256) void gemm16_kernel(
    const _Float16* __restrict__ A, const _Float16* __restrict__ Bt,
    const float* __restrict__ bias, OUTT* __restrict__ C,
    int M, int N, int K, int ldC)
{
    __shared__ _Float16 aS[64][4][8];
    __shared__ _Float16 bS[64][4][8];
    const int n0 = blockIdx.x * 64, m0 = blockIdx.y * 64;
    const int tid = threadIdx.x;
    const int wv = tid >> 6, ln = tid & 63;
    const int wm = wv & 1, wn = wv >> 1;
    const int lm = ln & 15, lq = ln >> 4;
    const int sr = tid >> 2, sq = tid & 3;

    f32x4 acc[2][2];
#pragma unroll
    for (int i = 0; i < 2; ++i)
#pragma unroll
        for (int j = 0; j < 2; ++j) acc[i][j] = (f32x4){0.f, 0.f, 0.f, 0.f};

    for (int cc = 0; cc < K; cc += 32) {
        *(uint4*)&aS[sr][sq][0] = *(const uint4*)(A + (size_t)(m0 + sr) * K + cc + sq * 8);
        uint4 bv = make_uint4(0u, 0u, 0u, 0u);
        if (n0 + sr < N)
            bv = *(const uint4*)(Bt + (size_t)(n0 + sr) * K + cc + sq * 8);
        *(uint4*)&bS[sr][sq][0] = bv;
        __syncthreads();
        f16x8 af[2], bf[2];
#pragma unroll
        for (int mt = 0; mt < 2; ++mt) af[mt] = *(const f16x8*)&aS[wm * 32 + mt * 16 + lm][lq][0];
#pragma unroll
        for (int nt = 0; nt < 2; ++nt) bf[nt] = *(const f16x8*)&bS[wn * 32 + nt * 16 + lm][lq][0];
#pragma unroll
        for (int mt = 0; mt < 2; ++mt)
#pragma unroll
            for (int nt = 0; nt < 2; ++nt)
                acc[mt][nt] = __builtin_amdgcn_mfma_f32_16x16x32_f16(af[mt], bf[nt], acc[mt][nt], 0, 0, 0);
        __syncthreads();
    }

#pragma unroll
    for (int mt = 0; mt < 2; ++mt) {
#pragma unroll
        for (int nt = 0; nt < 2; ++nt) {
            int col = n0 + wn * 32 + nt * 16 + lm;
            if (col >= N) continue;
            float bs = bias ? bias[col] : 0.f;
#pragma unroll
            for (int r = 0; r < 4; ++r) {
                int row = m0 + wm * 32 + mt * 16 + lq * 4 + r;
                float v = acc[mt][nt][r] + bs;
                if (ACT == 1) v = fmaxf(v, 0.f);
                if (ACT == 2) v = (v >= 0.f) ? v : 0.01f * v;
                C[(size_t)row * ldC + col] = (OUTT)v;
            }
        }
    }
}

// dual-B variant: grid.z selects (Bt, C). ACT=0, float out, no bias.
__global__ __launch_bounds__(256) void gemm16z_kernel(
    const _Float16* __restrict__ A,
    const _Float16* __restrict__ Bt0, const _Float16* __restrict__ Bt1,
    float* __restrict__ C0, float* __restrict__ C1,
    int M, int N, int K, int ldC)
{
    const _Float16* __restrict__ Bt = blockIdx.z ? Bt1 : Bt0;
    float* __restrict__ C = blockIdx.z ? C1 : C0;
    __shared__ _Float16 aS[64][4][8];
    __shared__ _Float16 bS[64][4][8];
    const int n0 = blockIdx.x * 64, m0 = blockIdx.y * 64;
    const int tid = threadIdx.x;
    const int wv = tid >> 6, ln = tid & 63;
    const int wm = wv & 1, wn = wv >> 1;
    const int lm = ln & 15, lq = ln >> 4;
    const int sr = tid >> 2, sq = tid & 3;

    f32x4 acc[2][2];
#pragma unroll
    for (int i = 0; i < 2; ++i)
#pragma unroll
        for (int j = 0; j < 2; ++j) acc[i][j] = (f32x4){0.f, 0.f, 0.f, 0.f};

    for (int cc = 0; cc < K; cc += 32) {
        *(uint4*)&aS[sr][sq][0] = *(const uint4*)(A + (size_t)(m0 + sr) * K + cc + sq * 8);
        uint4 bv = make_uint4(0u, 0u, 0u, 0u);
        if (n0 + sr < N)
            bv = *(const uint4*)(Bt + (size_t)(n0 + sr) * K + cc + sq * 8);
        *(uint4*)&bS[sr][sq][0] = bv;
        __syncthreads();
        f16x8 af[2], bf[2];
#pragma unroll
        for (int mt = 0; mt < 2; ++mt) af[mt] = *(const f16x8*)&aS[wm * 32 + mt * 16 + lm][lq][0];
#pragma unroll
        for (int nt = 0; nt < 2; ++nt) bf[nt] = *(const f16x8*)&bS[wn * 32 + nt * 16 + lm][lq][0];
#pragma unroll
        for (int mt = 0; mt < 2; ++mt)
#pragma unroll
            for (int nt = 0; nt < 2; ++nt)
                acc[mt][nt] = __builtin_amdgcn_mfma_f32_16x16x32_f16(af[mt], bf[nt], acc[mt][nt], 0, 0, 0);
        __syncthreads();
    }

#pragma unroll
    for (int mt = 0; mt < 2; ++mt) {
#pragma unroll
        for (int nt = 0; nt < 2; ++nt) {
            int col = n0 + wn * 32 + nt * 16 + lm;
            if (col >= N) continue;
#pragma unroll
            for (int r = 0; r < 4; ++r) {
                int row = m0 + wm * 32 + mt * 16 + lq * 4 + r;
                C[(size_t)row * ldC + col] = acc[mt][nt][r];
            }
        }
    }
}

// ---------------------------------------------------------------------------
// shared helper: per-sel centers sv[512] (LDS) + table extent tbv.
// ---------------------------------------------------------------------------
__device__ __forceinline__ float compute_sv_tb(
    const float* __restrict__ boxes, const float* __restrict__ scales,
    const float* __restrict__ pdls, const float* __restrict__ pdts,
    int b, int t, float* sv, float* red)
{
    int tid = threadIdx.x;
    float pdl = pdls[b], pdt = pdts[b], sc = scales[b];
    if (tid < 512) {
        const float* bx = boxes + (size_t)(b * 512 + tid) * 4;
        float o0 = (bx[0] - pdl) / sc;
        float o1 = (bx[1] - pdt) / sc;
        float o2 = (bx[2] - pdl) / sc;
        float o3 = (bx[3] - pdt) / sc;
        sv[tid]  = (t == 0) ? (o1 + o3) * 0.5f : (o0 + o2) * 0.5f;
        red[tid] = (t == 0) ? fmaxf(o1, o3)    : fmaxf(o0, o2);
    }
    __syncthreads();
    for (int s = 256; s > 0; s >>= 1) {
        if (tid < s) red[tid] = fmaxf(red[tid], red[tid + s]);
        __syncthreads();
    }
    float tbv = red[0];
    __syncthreads();
    return tbv;
}

#define QBITS(e, QB)                                                   \
    {                                                                  \
        int i_ = (e) / 511; int jj_ = (e) - i_ * 511;                  \
        int j_ = jj_ + (jj_ >= i_ ? 1 : 0);                            \
        float diff_ = sv[i_] - sv[j_];                                 \
        float u_ = (diff_ * 5.0f) / tbv;                               \
        float q_ = u_ * u_;                                            \
        QB = __float_as_uint(q_);                                      \
    }

// ---------------------------------------------------------------------------
// histA: LDS 4096-bin hist of top-12 q-bits, per-chunk partial.
// ---------------------------------------------------------------------------
__global__ __launch_bounds__(1024) void histA_kernel(
    const float* __restrict__ boxes, const float* __restrict__ scales,
    const float* __restrict__ pdls, const float* __restrict__ pdts,
    u32* __restrict__ gpart)
{
    __shared__ float sv[512]; __shared__ float red[512];
    __shared__ u32 lh[4096];
    const int sel = blockIdx.y, b = sel >> 1, t = sel & 1;
    const int tid = threadIdx.x;
    for (int i = tid; i < 4096; i += 1024) lh[i] = 0;
    const float tbv = compute_sv_tb(boxes, scales, pdls, pdts, b, t, sv, red);
    const int e1 = min((int)(blockIdx.x + 1) * ECHUNK, NE);
    for (int e = blockIdx.x * ECHUNK + tid; e < e1; e += 1024) {
        u32 qb; QBITS(e, qb);
        atomicAdd(&lh[qb >> 20], 1u);
    }
    __syncthreads();
    u32* G = gpart + ((size_t)sel * NCHUNK + blockIdx.x) * 4096;
    for (int i = tid; i < 4096; i += 1024) G[i] = lh[i];
}

// scanA: sum partials, block scan over 4096 bins, locate K-th -> p12, need1.
__global__ __launch_bounds__(1024) void scanA_kernel(
    const u32* __restrict__ gpart, u32* __restrict__ meta)
{
    const int sel = blockIdx.x, tid = threadIdx.x;
    __shared__ u32 bins[4096];
    __shared__ u32 sc[2][1024];
    for (int b = tid; b < 4096; b += 1024) {
        u32 s = 0;
        for (int c = 0; c < NCHUNK; ++c) s += gpart[((size_t)sel * NCHUNK + c) * 4096 + b];
        bins[b] = s;
    }
    __syncthreads();
    u32 part = 0;
#pragma unroll
    for (int j = 0; j < 4; ++j) part += bins[tid * 4 + j];
    sc[0][tid] = part;
    __syncthreads();
    int src = 0;
    for (int st = 1; st < 1024; st <<= 1) {
        sc[1 - src][tid] = sc[src][tid] + (tid >= st ? sc[src][tid - st] : 0);
        __syncthreads(); src = 1 - src;
    }
    u32 inc = sc[src][tid], exc = inc - part;
    if (exc < (u32)KEDGE && (u32)KEDGE <= inc) {
        u32 cum = exc;
        for (int j = 0; j < 4; ++j) {
            u32 c = bins[tid * 4 + j];
            if (cum + c >= (u32)KEDGE) {
                meta[sel * MS + 0] = (u32)(tid * 4 + j);
                meta[sel * MS + 1] = (u32)KEDGE - cum;
                break;
            }
            cum += c;
        }
    }
}

// histB: among edges with top-12 == p12, LDS hist of bits [19:8].
__global__ __launch_bounds__(1024) void histB_kernel(
    const float* __restrict__ boxes, const float* __restrict__ scales,
    const float* __restrict__ pdls, const float* __restrict__ pdts,
    const u32* __restrict__ meta, u32* __restrict__ gpart)
{
    __shared__ float sv[512]; __shared__ float red[512];
    __shared__ u32 lh[4096];
    const int sel = blockIdx.y, b = sel >> 1, t = sel & 1;
    const int tid = threadIdx.x;
    for (int i = tid; i < 4096; i += 1024) lh[i] = 0;
    const float tbv = compute_sv_tb(boxes, scales, pdls, pdts, b, t, sv, red);
    const u32 p12 = meta[sel * MS + 0];
    const int e1 = min((int)(blockIdx.x + 1) * ECHUNK, NE);
    for (int e = blockIdx.x * ECHUNK + tid; e < e1; e += 1024) {
        u32 qb; QBITS(e, qb);
        if ((qb >> 20) == p12) atomicAdd(&lh[(qb >> 8) & 0xFFF], 1u);
    }
    __syncthreads();
    u32* G = gpart + ((size_t)sel * NCHUNK + blockIdx.x) * 4096;
    for (int i = tid; i < 4096; i += 1024) G[i] = lh[i];
}

// scanB: locate need1-th within p12 group -> prefix24, need2.
__global__ __launch_bounds__(1024) void scanB_kernel(
    const u32* __restrict__ gpart, u32* __restrict__ meta)
{
    const int sel = blockIdx.x, tid = threadIdx.x;
    const u32 TH = meta[sel * MS + 1];
    __shared__ u32 bins[4096];
    __shared__ u32 sc[2][1024];
    for (int b = tid; b < 4096; b += 1024) {
        u32 s = 0;
        for (int c = 0; c < NCHUNK; ++c) s += gpart[((size_t)sel * NCHUNK + c) * 4096 + b];
        bins[b] = s;
    }
    __syncthreads();
    u32 part = 0;
#pragma unroll
    for (int j = 0; j < 4; ++j) part += bins[tid * 4 + j];
    sc[0][tid] = part;
    __syncthreads();
    int src = 0;
    for (int st = 1; st < 1024; st <<= 1) {
        sc[1 - src][tid] = sc[src][tid] + (tid >= st ? sc[src][tid - st] : 0);
        __syncthreads(); src = 1 - src;
    }
    u32 inc = sc[src][tid], exc = inc - part;
    if (exc < TH && TH <= inc) {
        u32 cum = exc;
        for (int j = 0; j < 4; ++j) {
            u32 c = bins[tid * 4 + j];
            if (cum + c >= TH) {
                meta[sel * MS + 6] = (meta[sel * MS + 0] << 12) | (u32)(tid * 4 + j);
                meta[sel * MS + 7] = TH - cum;
                break;
            }
            cum += c;
        }
    }
}

// histC: among edges with top-24 == prefix24, LDS hist of low 8 bits.
__global__ __launch_bounds__(1024) void histC_kernel(
    const float* __restrict__ boxes, const float* __restrict__ scales,
    const float* __restrict__ pdls, const float* __restrict__ pdts,
    const u32* __restrict__ meta, u32* __restrict__ gpart)
{
    __shared__ float sv[512]; __shared__ float red[512];
    __shared__ u32 lh[256];
    const int sel = blockIdx.y, b = sel >> 1, t = sel & 1;
    const int tid = threadIdx.x;
    if (tid < 256) lh[tid] = 0;
    const float tbv = compute_sv_tb(boxes, scales, pdls, pdts, b, t, sv, red);
    const u32 p24 = meta[sel * MS + 6];
    const int e1 = min((int)(blockIdx.x + 1) * ECHUNK, NE);
    for (int e = blockIdx.x * ECHUNK + tid; e < e1; e += 1024) {
        u32 qb; QBITS(e, qb);
        if ((qb >> 8) == p24) atomicAdd(&lh[qb & 0xFF], 1u);
    }
    __syncthreads();
    u32* G = gpart + ((size_t)sel * NCHUNK + blockIdx.x) * 256;
    if (tid < 256) G[tid] = lh[tid];
}

// scanC: exact q*, then binary-search the w*-tie q-interval [qlo,qhi].
__global__ __launch_bounds__(256) void scanC_kernel(
    const u32* __restrict__ gpart, u32* __restrict__ meta)
{
    const int sel = blockIdx.x, tid = threadIdx.x;
    const u32 TH = meta[sel * MS + 7];
    __shared__ u32 bins[256];
    __shared__ u32 sc[2][256];
    __shared__ u32 s_qstar;
    u32 s = 0;
    for (int c = 0; c < NCHUNK; ++c) s += gpart[((size_t)sel * NCHUNK + c) * 256 + tid];
    bins[tid] = s;
    sc[0][tid] = s;
    __syncthreads();
    int src = 0;
    for (int st = 1; st < 256; st <<= 1) {
        sc[1 - src][tid] = sc[src][tid] + (tid >= st ? sc[src][tid - st] : 0);
        __syncthreads(); src = 1 - src;
    }
    u32 inc = sc[src][tid], exc = inc - bins[tid];
    if (exc < TH && TH <= inc)
        s_qstar = (meta[sel * MS + 6] << 8) | (u32)tid;
    __syncthreads();
    if (tid == 0) {
        u32 prefix = s_qstar;
        float qstar = __uint_as_float(prefix);
        float wstar = (float)exp(-(double)qstar);
        u32 lo = 0, hi = prefix;              // smallest qb with exp(-q)==w*
        while (lo < hi) {
            u32 mid = (lo + hi) >> 1;
            float wm = (float)exp(-(double)__uint_as_float(mid));
            if (wm > wstar) lo = mid + 1; else hi = mid;
        }
        meta[sel * MS + 2] = lo;
        lo = prefix; hi = 0x7F800000u;        // largest qb with exp(-q)==w*
        while (lo < hi) {
            u32 mid = (lo + hi + 1) >> 1;
            float wm = (float)exp(-(double)__uint_as_float(mid));
            if (wm < wstar) hi = mid - 1; else lo = mid;
        }
        meta[sel * MS + 3] = lo;
        meta[sel * MS + 4] = __float_as_uint(wstar);
    }
}

// ---------------------------------------------------------------------------
// emit: two-pass block-aggregated slot reservation. Winners -> es/ed/ewt;
// ties -> tiebuf.
// ---------------------------------------------------------------------------
__global__ __launch_bounds__(1024) void emit_kernel(
    const float* __restrict__ boxes, const float* __restrict__ scales,
    const float* __restrict__ pdls, const float* __restrict__ pdts,
    u32* __restrict__ meta, int* __restrict__ tiebuf, int* __restrict__ tiecnt,
    int* __restrict__ es, int* __restrict__ ed, float* __restrict__ ewt,
    int* __restrict__ indeg, float* __restrict__ degw)
{
    __shared__ float sv[512]; __shared__ float red[512];
    __shared__ int s_wcnt, s_tcnt, s_wbase, s_tbase;
    const int sel = blockIdx.y, b = sel >> 1, t = sel & 1;
    const int tid = threadIdx.x;
    const float tbv = compute_sv_tb(boxes, scales, pdls, pdts, b, t, sv, red);
    const u32 qlo = meta[sel * MS + 2], qhi = meta[sel * MS + 3];
    const int base = t * 16384 + b * 4096;
    const int e0 = blockIdx.x * ECHUNK + tid;
    const int e1 = min((int)(blockIdx.x + 1) * ECHUNK, NE);
    if (tid == 0) { s_wcnt = 0; s_tcnt = 0; }
    __syncthreads();
    int myw = 0, myt = 0;
    for (int e = e0; e < e1; e += 1024) {
        u32 qb; QBITS(e, qb);
        if (qb < qlo) ++myw;
        else if (qb <= qhi) ++myt;
    }
    if (myw) atomicAdd(&s_wcnt, myw);
    if (myt) atomicAdd(&s_tcnt, myt);
    __syncthreads();
    if (tid == 0) {
        s_wbase = (s_wcnt > 0) ? (int)atomicAdd(&meta[sel * MS + 5], (u32)s_wcnt) : 0;
        s_tbase = (s_tcnt > 0) ? atomicAdd(&tiecnt[sel * TS], s_tcnt) : 0;
        s_wcnt = 0; s_tcnt = 0;
    }
    __syncthreads();
    for (int e = e0; e < e1; e += 1024) {
        u32 qb; QBITS(e, qb);
        if (qb < qlo) {
            int i = e / 511; int jj = e - i * 511; int j = jj + (jj >= i ? 1 : 0);
            float wval = (float)exp(-(double)__uint_as_float(qb));
            int slot = s_wbase + atomicAdd(&s_wcnt, 1);
            es[base + slot] = b * 512 + i;
            ed[base + slot] = b * 512 + j;
            ewt[base + slot] = wval;
            atomicAdd(&indeg[t * 2048 + b * 512 + j], 1);
            atomicAdd(&degw[t * 2048 + b * 512 + j], wval);
        } else if (qb <= qhi) {
            int p = s_tbase + atomicAdd(&s_tcnt, 1);
            if (p < TIECAP) tiebuf[sel * TIECAP + p] = e;
        }
    }
}

// ---------------------------------------------------------------------------
// tie resolution (index-ascending, r = K - emitted) + indeg scan + dis.
// ---------------------------------------------------------------------------
__global__ __launch_bounds__(1024) void tie_scan_kernel(
    u32* __restrict__ meta, const int* __restrict__ tiebuf, const int* __restrict__ tiecnt,
    int* __restrict__ es, int* __restrict__ ed, float* __restrict__ ewt,
    int* __restrict__ indeg, float* __restrict__ degw,
    int* __restrict__ offs, float* __restrict__ dis)
{
    __shared__ int bufA[2048], bufB[2048];
    const int t = blockIdx.x, tid = threadIdx.x;
    for (int b = 0; b < 4; ++b) {
        int sel = b * 2 + t;
        int m = min(tiecnt[sel * TS], TIECAP);
        int r = KEDGE - (int)meta[sel * MS + 5];
        float wt = __uint_as_float(meta[sel * MS + 4]);
        int base = t * 16384 + b * 4096;
        for (int k = tid; k < m; k += 1024) {
            int e = tiebuf[sel * TIECAP + k];
            int rank = 0;
            for (int l = 0; l < m; ++l) rank += (tiebuf[sel * TIECAP + l] < e) ? 1 : 0;
            if (rank < r) {
                int i = e / 511; int jj = e - i * 511; int j = jj + (jj >= i ? 1 : 0);
                int slot = (int)atomicAdd(&meta[sel * MS + 5], 1u);
                es[base + slot] = b * 512 + i;
                ed[base + slot] = b * 512 + j;
                ewt[base + slot] = wt;
                atomicAdd(&indeg[t * 2048 + b * 512 + j], 1);
                atomicAdd(&degw[t * 2048 + b * 512 + j], wt);
            }
        }
    }
    __threadfence();
    __syncthreads();
    bufA[tid] = indeg[t * 2048 + tid];
    bufA[tid + 1024] = indeg[t * 2048 + tid + 1024];
    __syncthreads();
    int* src = bufA; int* dst = bufB;
    for (int st = 1; st < 2048; st <<= 1) {
        dst[tid] = src[tid] + (tid >= st ? src[tid - st] : 0);
        int k1 = tid + 1024;
        dst[k1] = src[k1] + (k1 >= st ? src[k1 - st] : 0);
        __syncthreads();
        int* tmp = src; src = dst; dst = tmp;
    }
    offs[t * 2048 + tid] = (tid == 0) ? 0 : src[tid - 1];
    offs[t * 2048 + tid + 1024] = src[tid + 1023];
    dis[t * 2048 + tid] = 1.0f / sqrtf(1.0f + degw[t * 2048 + tid]);
    dis[t * 2048 + tid + 1024] = 1.0f / sqrtf(1.0f + degw[t * 2048 + tid + 1024]);
}

// CSR fill
__global__ void fill_kernel(const int* __restrict__ ed, const int* __restrict__ offs,
                            int* __restrict__ fill, int* __restrict__ csr) {
    int idx = blockIdx.x * 256 + threadIdx.x;
    if (idx >= 32768) return;
    int t = idx >> 14, e = idx & 16383;
    int d = ed[t * 16384 + e] & 2047;
    int pos = offs[t * 2048 + d] + atomicAdd(&fill[t * 2048 + d], 1);
    csr[t * 16384 + pos] = e;
}

// E7: GCN aggregate -> feats f16
__global__ __launch_bounds__(256) void gcn_agg_kernel(
    const float* __restrict__ xw_row, const float* __restrict__ xw_col,
    const float* __restrict__ b_row, const float* __restrict__ b_col,
    const int* __restrict__ es, const float* __restrict__ ew,
    const int* __restrict__ csr, const int* __restrict__ offs,
    const int* __restrict__ indeg, const float* __restrict__ dis,
    _Float16* __restrict__ feat_row, _Float16* __restrict__ feat_col)
{
    int d = blockIdx.x; int t = blockIdx.y;
    const float* xw = t ? xw_col : xw_row;
    const float* bg = t ? b_col : b_row;
    _Float16* out = t ? feat_col : feat_row;
    int f0 = threadIdx.x, f1 = threadIdx.x + 256;
    float dd = dis[t * 2048 + d];
    float a0 = dd * dd * xw[(size_t)d * 512 + f0];
    float a1 = dd * dd * xw[(size_t)d * 512 + f1];
    int st = offs[t * 2048 + d], cnt = indeg[t * 2048 + d];
    for (int k = 0; k < cnt; ++k) {
        int e = csr[t * 16384 + st + k];
        int s = es[t * 16384 + e];
        float w = ew[t * 16384 + e];
        float coef = dis[t * 2048 + s] * w * dd;
        a0 += coef * xw[(size_t)s * 512 + f0];
        a1 += coef * xw[(size_t)s * 512 + f1];
    }
    a0 += bg[f0]; a1 += bg[f1];
    out[(size_t)d * 512 + f0] = (_Float16)fmaxf(a0, 0.f);
    out[(size_t)d * 512 + f1] = (_Float16)fmaxf(a1, 0.f);
}

// ---------------------------------------------------------------------------
extern "C" void kernel_launch(void* const* d_in, const int* in_sizes, int n_in,
                              void* d_out, int out_size, void* d_ws, size_t ws_size,
                              hipStream_t stream)
{
    const float* x      = (const float*)d_in[0];
    const float* boxes  = (const float*)d_in[1];
    const float* scales = (const float*)d_in[2];
    const float* pdls   = (const float*)d_in[3];
    const float* pdts   = (const float*)d_in[4];
    const float* W_dec  = (const float*)d_in[5];
    const float* b_dec  = (const float*)d_in[6];
    const float* W_box  = (const float*)d_in[7];
    const float* b_box  = (const float*)d_in[8];
    const float* W_cnn  = (const float*)d_in[9];
    const float* b_cnn  = (const float*)d_in[10];
    const float* W_grow = (const float*)d_in[11];
    const float* b_grow = (const float*)d_in[12];
    const float* W_gcol = (const float*)d_in[13];
    const float* b_gcol = (const float*)d_in[14];
    const float* W_rcls = (const float*)d_in[15];
    const float* b_rcls = (const float*)d_in[16];
    const float* W_ccls = (const float*)d_in[17];
    const float* b_ccls = (const float*)d_in[18];

    char* ws = (char*)d_ws;
    size_t off = 0;
    auto alloc = [&](size_t bytes) -> void* {
        void* p = ws + off;
        off = (off + bytes + 255) & ~(size_t)255;
        return p;
    };
    _Float16* xf16   = (_Float16*)alloc((size_t)4 * 2304 * 1024 * 2);  // NHWC in
    _Float16* wf16   = (_Float16*)alloc((size_t)256 * 9216 * 2);       // [o][tap][ch]
    _Float16* dec    = (_Float16*)alloc((size_t)4 * 2304 * 256 * 2);   // NHWC
    float*    pbuf   = (float*)   alloc((size_t)4 * PSLICE * 4);       // split-K(4) partials
    _Float16* cnn    = (_Float16*)alloc((size_t)2048 * 1024 * 2);
    _Float16* fusion = (_Float16*)alloc((size_t)2048 * 768 * 2);
    _Float16* WcT    = (_Float16*)alloc((size_t)512 * 1024 * 2);
    _Float16* WgrT   = (_Float16*)alloc((size_t)512 * 768 * 2);
    _Float16* WgcT   = (_Float16*)alloc((size_t)512 * 768 * 2);
    _Float16* WrT    = (_Float16*)alloc((size_t)228 * 512 * 2);
    _Float16* WccT   = (_Float16*)alloc((size_t)116 * 512 * 2);
    float* xw        = (float*)alloc((size_t)2097152 * 4);             // xw_row|xw_col
    _Float16* feats  = (_Float16*)alloc((size_t)2 * 2048 * 512 * 2);   // row|col
    int*  es     = (int*)  alloc((size_t)2 * 16384 * 4);
    int*  ed     = (int*)  alloc((size_t)2 * 16384 * 4);
    float* ewt   = (float*)alloc((size_t)2 * 16384 * 4);
    int*  offsA  = (int*)  alloc((size_t)4096 * 4);
    float* dis   = (float*)alloc((size_t)4096 * 4);
    int*  csr    = (int*)  alloc((size_t)2 * 16384 * 4);
    int*  tiebuf = (int*)  alloc((size_t)8 * TIECAP * 4);
    u32*  gpartA = (u32*)  alloc((size_t)8 * NCHUNK * 4096 * 4);   // fully overwritten
    u32*  gpartB = (u32*)  alloc((size_t)8 * NCHUNK * 4096 * 4);
    u32*  gpartC = (u32*)  alloc((size_t)8 * NCHUNK * 256 * 4);
    // ---- zero zone (one hipMemsetAsync) ----
    size_t z0 = off;
    u32*  meta   = (u32*)  alloc((size_t)8 * MS * 4);
    int*  tiecnt = (int*)  alloc((size_t)8 * TS * 4);
    int*  indeg  = (int*)  alloc((size_t)4096 * 4);
    float* degw  = (float*)alloc((size_t)4096 * 4);
    int*  fillA  = (int*)  alloc((size_t)4096 * 4);
    size_t z1 = off;

    float* out = (float*)d_out;

    hipMemsetAsync(ws + z0, 0, z1 - z0, stream);

    cvt_x_kernel<<<dim3(16, 48, 4), 256, 0, stream>>>(x, xf16);
    cvt_w_kernel<<<256, 256, 0, stream>>>(W_dec, wf16);
    conv_part_kernel<<<dim3(6, 4, 16), 256, 0, stream>>>(xf16, wf16, pbuf);
    conv_sum_kernel<<<2304, 256, 0, stream>>>(pbuf, b_dec, dec);
    roi_kernel<<<2048, 256, 0, stream>>>(dec, boxes, cnn);
    box_kernel<<<2048, 256, 0, stream>>>(boxes, W_box, b_box, fusion);
    // weight transposes (f16 [N][K])
    cvt_t_kernel<<<dim3(16, 32), 256, 0, stream>>>(W_cnn, WcT, 1024, 512);
    cvt_t_kernel<<<dim3(16, 24), 256, 0, stream>>>(W_grow, WgrT, 768, 512);
    cvt_t_kernel<<<dim3(16, 24), 256, 0, stream>>>(W_gcol, WgcT, 768, 512);
    cvt_t_kernel<<<dim3(8, 16), 256, 0, stream>>>(W_rcls, WrT, 512, 228);
    cvt_t_kernel<<<dim3(4, 16), 256, 0, stream>>>(W_ccls, WccT, 512, 116);
    // fusion[:,256:768] = relu(cnn @ W_cnn + b)
    gemm16_kernel<1, _Float16><<<dim3(8, 32), 256, 0, stream>>>(cnn, WcT, b_cnn, fusion + 256, 2048, 512, 1024, 768);
    // edge pipeline: 12+12+8 LDS-privatized radix select + emit + CSR
    histA_kernel<<<dim3(NCHUNK, 8), 1024, 0, stream>>>(boxes, scales, pdls, pdts, gpartA);
    scanA_kernel<<<8, 1024, 0, stream>>>(gpartA, meta);
    histB_kernel<<<dim3(NCHUNK, 8), 1024, 0, stream>>>(boxes, scales, pdls, pdts, meta, gpartB);
    scanB_kernel<<<8, 1024, 0, stream>>>(gpartB, meta);
    histC_kernel<<<dim3(NCHUNK, 8), 1024, 0, stream>>>(boxes, scales, pdls, pdts, meta, gpartC);
    scanC_kernel<<<8, 256, 0, stream>>>(gpartC, meta);
    emit_kernel<<<dim3(NCHUNK, 8), 1024, 0, stream>>>(boxes, scales, pdls, pdts, meta,
                                                      tiebuf, tiecnt, es, ed, ewt, indeg, degw);
    tie_scan_kernel<<<2, 1024, 0, stream>>>(meta, tiebuf, tiecnt, es, ed, ewt,
                                            indeg, degw, offsA, dis);
    fill_kernel<<<128, 256, 0, stream>>>(ed, offsA, fillA, csr);
    // xw = fusion @ W_g{row,col} (bias applied in aggregation) — one dual launch
    gemm16z_kernel<<<dim3(8, 32, 2), 256, 0, stream>>>(fusion, WgrT, WgcT, xw, xw + 1048576,
                                                       2048, 512, 768, 512);
    gcn_agg_kernel<<<dim3(2048, 2), 256, 0, stream>>>(xw, xw + 1048576, b_grow, b_gcol,
                                                      es, ewt, csr, offsA, indeg, dis,
                                                      feats, feats + (size_t)2048 * 512);
    // classifier heads (leaky 0.01) -> fp32 out
    gemm16_kernel<2, float><<<dim3(4, 32), 256, 0, stream>>>(feats, WrT, b_rcls, out, 2048, 228, 512, 228);
    gemm16_kernel<2, float><<<dim3(2, 32), 256, 0, stream>>>(feats + (size_t)2048 * 512, WccT, b_ccls,
                                                             out + (size_t)2048 * 228, 2048, 116, 512, 116);
}

// Round 14
// 380.999 us; speedup vs baseline: 1.1046x; 1.1046x over previous
//
#include <hip/hip_runtime.h>
#include <cstdint>
#include <math.h>

typedef unsigned int u32;
typedef unsigned long long u64;
typedef unsigned short ushort;

typedef __attribute__((ext_vector_type(8))) _Float16 f16x8;
typedef __attribute__((ext_vector_type(4))) _Float16 f16x4;
typedef __attribute__((ext_vector_type(4))) float f32x4;

#define NB    4
#define BnN   2048
#define NE    261632      // 512*511 ordered pairs per batch
#define NCHUNK 16
#define ECHUNK 16352      // NE/16
#define KEDGE 4096
#define TIECAP 2048
#define PSLICE 2359296    // 4*2304*256 elements per K-slice partial
#define MS    64          // meta stride (u32) per sel -> 256B, own cache lines
#define TS    64          // tiecnt stride (int) per sel

// meta[sel*MS+i]: 0:p12  1:need1  2:qlo  3:qhi  4:wstar  5:emitcnt  6:prefix24  7:need2
// ---------------------------------------------------------------------------
// convert input: NCHW fp32 -> NHWC f16.  grid (16 chgrp, 48 y, 4 b), block 256
// ---------------------------------------------------------------------------
__global__ __launch_bounds__(256) void cvt_x_kernel(
    const float* __restrict__ in, _Float16* __restrict__ xf)
{
    __shared__ _Float16 sh[64][49];
    int cg = blockIdx.x, y = blockIdx.y, b = blockIdx.z;
    int tid = threadIdx.x;
    for (int i = tid; i < 64 * 48; i += 256) {
        int cl = i / 48, x = i - cl * 48;
        sh[cl][x] = (_Float16)in[(((size_t)b * 1024 + cg * 64 + cl) * 48 + y) * 48 + x];
    }
    __syncthreads();
    for (int i = tid; i < 64 * 48; i += 256) {
        int x = i / 64, cl = i - x * 64;
        xf[((size_t)(b * 48 + y) * 48 + x) * 1024 + cg * 64 + cl] = sh[cl][x];
    }
}

// convert weights: [o][ch][3][3] fp32 -> [o][tap][ch] f16. grid 256, block 256
__global__ __launch_bounds__(256) void cvt_w_kernel(
    const float* __restrict__ W, _Float16* __restrict__ wf)
{
    __shared__ _Float16 sh[9216];
    int o = blockIdx.x, tid = threadIdx.x;
    for (int g = tid; g < 9216; g += 256)
        sh[g] = (_Float16)W[(size_t)o * 9216 + g];     // g = ch*9+tap
    __syncthreads();
    for (int g = tid; g < 9216; g += 256) {
        int tap = g >> 10, ch = g & 1023;
        wf[(size_t)o * 9216 + g] = sh[ch * 9 + tap];
    }
}

// transpose-convert: in fp32 [K][N] -> out f16 [N][K]. grid (ceil(N/32), ceil(K/32))
__global__ __launch_bounds__(256) void cvt_t_kernel(
    const float* __restrict__ in, _Float16* __restrict__ out, int K, int N)
{
    __shared__ _Float16 sh[32][33];
    int n0 = blockIdx.x * 32, k0 = blockIdx.y * 32;
    int tx = threadIdx.x & 31, ty = threadIdx.x >> 5;
#pragma unroll
    for (int i = 0; i < 4; ++i) {
        int k = k0 + ty + i * 8, n = n0 + tx;
        sh[ty + i * 8][tx] = (k < K && n < N) ? (_Float16)in[(size_t)k * N + n] : (_Float16)0.f;
    }
    __syncthreads();
#pragma unroll
    for (int i = 0; i < 4; ++i) {
        int n = n0 + ty + i * 8, k = k0 + tx;
        if (n < N && k < K) out[(size_t)n * K + k] = sh[tx][ty + i * 8];
    }
}

// ---------------------------------------------------------------------------
// conv 3x3 SAME 1024->256, split-K(4) partials. Implicit-GEMM MFMA f16.
// Block 256 thr (4 waves). Wave tile: 32 och x 2 rows x 48 px.
// LDS = 18.4 + 32 = 50.4 KB -> 3 blocks/CU; grid (6,8,16) = 768 blocks =
// exactly 3/CU, perfectly balanced (R12's 384-block grid left half the CUs
// idle for the 2nd round). No pointer arrays / prefetch (R13 spilled).
// ---------------------------------------------------------------------------
__global__ __launch_bounds__(256) void conv_part_kernel(
    const _Float16* __restrict__ xf, const _Float16* __restrict__ wf,
    float* __restrict__ pbuf)
{
    __shared__ _Float16 wS[9][4][32][8];   // 18.4 KB  [tap][q][och32][8ch]
    __shared__ _Float16 xS[10][4][50][8];  // 32.0 KB  [row10][q][col][8ch]
    const int y0 = blockIdx.x * 8;
    const int og = blockIdx.y;             // 0..7 (32 och each)
    const int bz = blockIdx.z;
    const int b  = bz >> 2, ks = bz & 3;
    const int tid = threadIdx.x;
    const int wv = tid >> 6;
    const int ln = tid & 63;
    const int n  = ln & 15;
    const int q  = ln >> 4;

    f32x4 acc[2][2][3];
#pragma unroll
    for (int mt = 0; mt < 2; ++mt)
#pragma unroll
        for (int rr = 0; rr < 2; ++rr)
#pragma unroll
            for (int nt = 0; nt < 3; ++nt) acc[mt][rr][nt] = (f32x4){0.f, 0.f, 0.f, 0.f};

    const int c0 = ks * 256;
    for (int cc = c0; cc < c0 + 256; cc += 32) {
        // stage weights: 1152 x 16B
#pragma unroll
        for (int it = 0; it < 5; ++it) {
            int g = it * 256 + tid;
            if (g < 1152) {
                int tap = g >> 7, r = g & 127, qq = r >> 5, oc = r & 31;
                *(uint4*)&wS[tap][qq][oc][0] =
                    *(const uint4*)(wf + ((size_t)(og * 32 + oc) * 9 + tap) * 1024 + cc + qq * 8);
            }
        }
        // stage input rows y0-1 .. y0+8 (10), cols -1..48 : 2000 x 16B
#pragma unroll
        for (int it = 0; it < 8; ++it) {
            int g = it * 256 + tid;
            if (g < 2000) {
                int row = g / 200, r2 = g - row * 200;
                int qq = r2 / 50, c = r2 - qq * 50;
                int gy = y0 + row - 1, gx = c - 1;
                uint4 v = make_uint4(0u, 0u, 0u, 0u);
                if ((unsigned)gy < 48u && (unsigned)gx < 48u)
                    v = *(const uint4*)(xf + ((size_t)(b * 48 + gy) * 48 + gx) * 1024 + cc + qq * 8);
                *(uint4*)&xS[row][qq][c][0] = v;
            }
        }
        __syncthreads();

#pragma unroll
        for (int tap = 0; tap < 9; ++tap) {
            const int dy = tap / 3, dx = tap % 3;
            f16x8 a0 = *(const f16x8*)&wS[tap][q][n][0];
            f16x8 a1 = *(const f16x8*)&wS[tap][q][16 + n][0];
#pragma unroll
            for (int rr = 0; rr < 2; ++rr) {
                const int row = 2 * wv + rr + dy;
#pragma unroll
                for (int nt = 0; nt < 3; ++nt) {
                    f16x8 bb = *(const f16x8*)&xS[row][q][nt * 16 + n + dx][0];
                    acc[0][rr][nt] = __builtin_amdgcn_mfma_f32_16x16x32_f16(a0, bb, acc[0][rr][nt], 0, 0, 0);
                    acc[1][rr][nt] = __builtin_amdgcn_mfma_f32_16x16x32_f16(a1, bb, acc[1][rr][nt], 0, 0, 0);
                }
            }
        }
        __syncthreads();
    }

    // epilogue: px = nt*16+n, och = og*32 + mt*16 + q*4 + reg, y = y0+2wv+rr
#pragma unroll
    for (int rr = 0; rr < 2; ++rr) {
        const int y = y0 + 2 * wv + rr;
#pragma unroll
        for (int mt = 0; mt < 2; ++mt) {
#pragma unroll
            for (int nt = 0; nt < 3; ++nt) {
                int x = nt * 16 + n;
                *(f32x4*)(pbuf + (size_t)ks * PSLICE +
                          ((size_t)(b * 48 + y) * 48 + x) * 256 + og * 32 + mt * 16 + q * 4) = acc[mt][rr][nt];
            }
        }
    }
}

// sum 4 partials + bias + relu -> dec NHWC f16. grid 2304 x 256.
__global__ __launch_bounds__(256) void conv_sum_kernel(
    const float* __restrict__ pbuf, const float* __restrict__ bd,
    _Float16* __restrict__ dec)
{
    size_t idx = (size_t)blockIdx.x * 256 + threadIdx.x;   // 589824 threads
    size_t e = idx * 4;
    int och = (int)(e & 255);
    f32x4 s0 = *(const f32x4*)(pbuf + e);
    f32x4 s1 = *(const f32x4*)(pbuf + (size_t)PSLICE + e);
    f32x4 s2 = *(const f32x4*)(pbuf + (size_t)2 * PSLICE + e);
    f32x4 s3 = *(const f32x4*)(pbuf + (size_t)3 * PSLICE + e);
    float4 b4 = *(const float4*)(bd + och);
    f16x4 v;
    v.x = (_Float16)fmaxf(s0[0] + s1[0] + s2[0] + s3[0] + b4.x, 0.f);
    v.y = (_Float16)fmaxf(s0[1] + s1[1] + s2[1] + s3[1] + b4.y, 0.f);
    v.z = (_Float16)fmaxf(s0[2] + s1[2] + s2[2] + s3[2] + b4.z, 0.f);
    v.w = (_Float16)fmaxf(s0[3] + s1[3] + s2[3] + s3[3] + b4.w, 0.f);
    *(f16x4*)(dec + e) = v;
}

// ---------------------------------------------------------------------------
// ROI align 2x2 on NHWC f16 dec
// ---------------------------------------------------------------------------
__global__ __launch_bounds__(256) void roi_kernel(
    const _Float16* __restrict__ dec, const float* __restrict__ boxes,
    _Float16* __restrict__ cnn)
{
    int n = blockIdx.x; int c = threadIdx.x;
    int b = n >> 9;
    float x1 = boxes[n * 4 + 0], y1 = boxes[n * 4 + 1];
    float x2 = boxes[n * 4 + 2], y2 = boxes[n * 4 + 3];
    float bw = (x2 - x1) * 0.5f, bh = (y2 - y1) * 0.5f;
    float sxv[2] = { x1 + 0.5f * bw, x1 + 1.5f * bw };
    float syv[2] = { y1 + 0.5f * bh, y1 + 1.5f * bh };
    float px[4] = { sxv[0], sxv[1], sxv[0], sxv[1] };
    float py[4] = { syv[0], syv[0], syv[1], syv[1] };
    const _Float16* f = dec + (size_t)b * 2304 * 256;
    f16x4 o4;
    float res[4];
#pragma unroll
    for (int p = 0; p < 4; ++p) {
        float yy = fminf(fmaxf(py[p], 0.f), 47.f);
        float xx = fminf(fmaxf(px[p], 0.f), 47.f);
        int y0 = (int)floorf(yy), x0 = (int)floorf(xx);
        int y1i = min(y0 + 1, 47), x1i = min(x0 + 1, 47);
        float wy = yy - (float)y0, wx = xx - (float)x0;
        float f00 = (float)f[(size_t)(y0 * 48 + x0) * 256 + c];
        float f01 = (float)f[(size_t)(y0 * 48 + x1i) * 256 + c];
        float f10 = (float)f[(size_t)(y1i * 48 + x0) * 256 + c];
        float f11 = (float)f[(size_t)(y1i * 48 + x1i) * 256 + c];
        res[p] = f00 * (1.f - wy) * (1.f - wx) + f01 * (1.f - wy) * wx
               + f10 * wy * (1.f - wx) + f11 * wy * wx;
    }
    o4.x = (_Float16)res[0]; o4.y = (_Float16)res[1];
    o4.z = (_Float16)res[2]; o4.w = (_Float16)res[3];
    *(f16x4*)(cnn + (size_t)n * 1024 + c * 4) = o4;
}

// ---------------------------------------------------------------------------
// box head: fusion[:, 0:256] = relu(bf @ W_box + b_box)
// ---------------------------------------------------------------------------
__global__ __launch_bounds__(256) void box_kernel(
    const float* __restrict__ boxes, const float* __restrict__ Wb,
    const float* __restrict__ bb, _Float16* __restrict__ fusion)
{
    int nrow = blockIdx.x, c = threadIdx.x;
    float x1 = boxes[nrow * 4 + 0], y1 = boxes[nrow * 4 + 1];
    float x2 = boxes[nrow * 4 + 2], y2 = boxes[nrow * 4 + 3];
    float bf0 = ((x1 + x2) * 0.5f) / 48.f;
    float bf1 = ((y1 + y2) * 0.5f) / 48.f;
    float bf2 = (x2 - x1) / 48.f;
    float bf3 = (y2 - y1) / 48.f;
    float acc = bb[c];
    acc += bf0 * Wb[0 * 256 + c];
    acc += bf1 * Wb[1 * 256 + c];
    acc += bf2 * Wb[2 * 256 + c];
    acc += bf3 * Wb[3 * 256 + c];
    fusion[(size_t)nrow * 768 + c] = (_Float16)fmaxf(acc, 0.f);
}

// ---------------------------------------------------------------------------
// f16 MFMA GEMM: C = act(A @ Bt^T + bias). 64x64 tile, 4 waves 2x2.
// ---------------------------------------------------------------------------
template <int ACT, typename OUTT>
__global__ __launch_bounds__(256) void gemm16_kernel(
    const _Float16* __restrict__ A, const _Float16* __restrict__ Bt,
    const float* __restrict__ bias, OUTT* __restrict__ C,
    int M, int N, int K, int ldC)
{
    __shared__ _Float16 aS[64][4][8];
    __shared__ _Float16 bS[64][4][8];
    const int n0 = blockIdx.x * 64, m0 = blockIdx.y * 64;
    const int tid = threadIdx.x;
    const int wv = tid >> 6, ln = tid & 63;
    const int wm = wv & 1, wn = wv >> 1;
    const int lm = ln & 15, lq = ln >> 4;
    const int sr = tid >> 2, sq = tid & 3;

    f32x4 acc[2][2];
#pragma unroll
    for (int i = 0; i < 2; ++i)
#pragma unroll
        for (int j = 0; j < 2; ++j) acc[i][j] = (f32x4){0.f, 0.f, 0.f, 0.f};

    for (int cc = 0; cc < K; cc += 32) {
        *(uint4*)&aS[sr][sq][0] = *(const uint4*)(A + (size_t)(m0 + sr) * K + cc + sq * 8);
        uint4 bv = make_uint4(0u, 0u, 0u, 0u);
        if (n0 + sr < N)
            bv = *(const uint4*)(Bt + (size_t)(n0 + sr) * K + cc + sq * 8);
        *(uint4*)&bS[sr][sq][0] = bv;
        __syncthreads();
        f16x8 af[2], bf[2];
#pragma unroll
        for (int mt = 0; mt < 2; ++mt) af[mt] = *(const f16x8*)&aS[wm * 32 + mt * 16 + lm][lq][0];
#pragma unroll
        for (int nt = 0; nt < 2; ++nt) bf[nt] = *(const f16x8*)&bS[wn * 32 + nt * 16 + lm][lq][0];
#pragma unroll
        for (int mt = 0; mt < 2; ++mt)
#pragma unroll
            for (int nt = 0; nt < 2; ++nt)
                acc[mt][nt] = __builtin_amdgcn_mfma_f32_16x16x32_f16(af[mt], bf[nt], acc[mt][nt], 0, 0, 0);
        __syncthreads();
    }

#pragma unroll
    for (int mt = 0; mt < 2; ++mt) {
#pragma unroll
        for (int nt = 0; nt < 2; ++nt) {
            int col = n0 + wn * 32 + nt * 16 + lm;
            if (col >= N) continue;
            float bs = bias ? bias[col] : 0.f;
#pragma unroll
            for (int r = 0; r < 4; ++r) {
                int row = m0 + wm * 32 + mt * 16 + lq * 4 + r;
                float v = acc[mt][nt][r] + bs;
                if (ACT == 1) v = fmaxf(v, 0.f);
                if (ACT == 2) v = (v >= 0.f) ? v : 0.01f * v;
                C[(size_t)row * ldC + col] = (OUTT)v;
            }
        }
    }
}

// dual-B variant: grid.z selects (Bt, C). ACT=0, float out, no bias.
__global__ __launch_bounds__(256) void gemm16z_kernel(
    const _Float16* __restrict__ A,
    const _Float16* __restrict__ Bt0, const _Float16* __restrict__ Bt1,
    float* __restrict__ C0, float* __restrict__ C1,
    int M, int N, int K, int ldC)
{
    const _Float16* __restrict__ Bt = blockIdx.z ? Bt1 : Bt0;
    float* __restrict__ C = blockIdx.z ? C1 : C0;
    __shared__ _Float16 aS[64][4][8];
    __shared__ _Float16 bS[64][4][8];
    const int n0 = blockIdx.x * 64, m0 = blockIdx.y * 64;
    const int tid = threadIdx.x;
    const int wv = tid >> 6, ln = tid & 63;
    const int wm = wv & 1, wn = wv >> 1;
    const int lm = ln & 15, lq = ln >> 4;
    const int sr = tid >> 2, sq = tid & 3;

    f32x4 acc[2][2];
#pragma unroll
    for (int i = 0; i < 2; ++i)
#pragma unroll
        for (int j = 0; j < 2; ++j) acc[i][j] = (f32x4){0.f, 0.f, 0.f, 0.f};

    for (int cc = 0; cc < K; cc += 32) {
        *(uint4*)&aS[sr][sq][0] = *(const uint4*)(A + (size_t)(m0 + sr) * K + cc + sq * 8);
        uint4 bv = make_uint4(0u, 0u, 0u, 0u);
        if (n0 + sr < N)
            bv = *(const uint4*)(Bt + (size_t)(n0 + sr) * K + cc + sq * 8);
        *(uint4*)&bS[sr][sq][0] = bv;
        __syncthreads();
        f16x8 af[2], bf[2];
#pragma unroll
        for (int mt = 0; mt < 2; ++mt) af[mt] = *(const f16x8*)&aS[wm * 32 + mt * 16 + lm][lq][0];
#pragma unroll
        for (int nt = 0; nt < 2; ++nt) bf[nt] = *(const f16x8*)&bS[wn * 32 + nt * 16 + lm][lq][0];
#pragma unroll
        for (int mt = 0; mt < 2; ++mt)
#pragma unroll
            for (int nt = 0; nt < 2; ++nt)
                acc[mt][nt] = __builtin_amdgcn_mfma_f32_16x16x32_f16(af[mt], bf[nt], acc[mt][nt], 0, 0, 0);
        __syncthreads();
    }

#pragma unroll
    for (int mt = 0; mt < 2; ++mt) {
#pragma unroll
        for (int nt = 0; nt < 2; ++nt) {
            int col = n0 + wn * 32 + nt * 16 + lm;
            if (col >= N) continue;
#pragma unroll
            for (int r = 0; r < 4; ++r) {
                int row = m0 + wm * 32 + mt * 16 + lq * 4 + r;
                C[(size_t)row * ldC + col] = acc[mt][nt][r];
            }
        }
    }
}

// ---------------------------------------------------------------------------
// shared helper: per-sel centers sv[512] (LDS) + table extent tbv.
// ---------------------------------------------------------------------------
__device__ __forceinline__ float compute_sv_tb(
    const float* __restrict__ boxes, const float* __restrict__ scales,
    const float* __restrict__ pdls, const float* __restrict__ pdts,
    int b, int t, float* sv, float* red)
{
    int tid = threadIdx.x;
    float pdl = pdls[b], pdt = pdts[b], sc = scales[b];
    if (tid < 512) {
        const float* bx = boxes + (size_t)(b * 512 + tid) * 4;
        float o0 = (bx[0] - pdl) / sc;
        float o1 = (bx[1] - pdt) / sc;
        float o2 = (bx[2] - pdl) / sc;
        float o3 = (bx[3] - pdt) / sc;
        sv[tid]  = (t == 0) ? (o1 + o3) * 0.5f : (o0 + o2) * 0.5f;
        red[tid] = (t == 0) ? fmaxf(o1, o3)    : fmaxf(o0, o2);
    }
    __syncthreads();
    for (int s = 256; s > 0; s >>= 1) {
        if (tid < s) red[tid] = fmaxf(red[tid], red[tid + s]);
        __syncthreads();
    }
    float tbv = red[0];
    __syncthreads();
    return tbv;
}

#define QBITS(e, QB)                                                   \
    {                                                                  \
        int i_ = (e) / 511; int jj_ = (e) - i_ * 511;                  \
        int j_ = jj_ + (jj_ >= i_ ? 1 : 0);                            \
        float diff_ = sv[i_] - sv[j_];                                 \
        float u_ = (diff_ * 5.0f) / tbv;                               \
        float q_ = u_ * u_;                                            \
        QB = __float_as_uint(q_);                                      \
    }

// ---------------------------------------------------------------------------
// histA: LDS 4096-bin hist of top-12 q-bits, per-chunk partial.
// ---------------------------------------------------------------------------
__global__ __launch_bounds__(1024) void histA_kernel(
    const float* __restrict__ boxes, const float* __restrict__ scales,
    const float* __restrict__ pdls, const float* __restrict__ pdts,
    u32* __restrict__ gpart)
{
    __shared__ float sv[512]; __shared__ float red[512];
    __shared__ u32 lh[4096];
    const int sel = blockIdx.y, b = sel >> 1, t = sel & 1;
    const int tid = threadIdx.x;
    for (int i = tid; i < 4096; i += 1024) lh[i] = 0;
    const float tbv = compute_sv_tb(boxes, scales, pdls, pdts, b, t, sv, red);
    const int e1 = min((int)(blockIdx.x + 1) * ECHUNK, NE);
    for (int e = blockIdx.x * ECHUNK + tid; e < e1; e += 1024) {
        u32 qb; QBITS(e, qb);
        atomicAdd(&lh[qb >> 20], 1u);
    }
    __syncthreads();
    u32* G = gpart + ((size_t)sel * NCHUNK + blockIdx.x) * 4096;
    for (int i = tid; i < 4096; i += 1024) G[i] = lh[i];
}

// scanA: sum partials, block scan over 4096 bins, locate K-th -> p12, need1.
__global__ __launch_bounds__(1024) void scanA_kernel(
    const u32* __restrict__ gpart, u32* __restrict__ meta)
{
    const int sel = blockIdx.x, tid = threadIdx.x;
    __shared__ u32 bins[4096];
    __shared__ u32 sc[2][1024];
    for (int b = tid; b < 4096; b += 1024) {
        u32 s = 0;
        for (int c = 0; c < NCHUNK; ++c) s += gpart[((size_t)sel * NCHUNK + c) * 4096 + b];
        bins[b] = s;
    }
    __syncthreads();
    u32 part = 0;
#pragma unroll
    for (int j = 0; j < 4; ++j) part += bins[tid * 4 + j];
    sc[0][tid] = part;
    __syncthreads();
    int src = 0;
    for (int st = 1; st < 1024; st <<= 1) {
        sc[1 - src][tid] = sc[src][tid] + (tid >= st ? sc[src][tid - st] : 0);
        __syncthreads(); src = 1 - src;
    }
    u32 inc = sc[src][tid], exc = inc - part;
    if (exc < (u32)KEDGE && (u32)KEDGE <= inc) {
        u32 cum = exc;
        for (int j = 0; j < 4; ++j) {
            u32 c = bins[tid * 4 + j];
            if (cum + c >= (u32)KEDGE) {
                meta[sel * MS + 0] = (u32)(tid * 4 + j);
                meta[sel * MS + 1] = (u32)KEDGE - cum;
                break;
            }
            cum += c;
        }
    }
}

// histB: among edges with top-12 == p12, LDS hist of bits [19:8].
__global__ __launch_bounds__(1024) void histB_kernel(
    const float* __restrict__ boxes, const float* __restrict__ scales,
    const float* __restrict__ pdls, const float* __restrict__ pdts,
    const u32* __restrict__ meta, u32* __restrict__ gpart)
{
    __shared__ float sv[512]; __shared__ float red[512];
    __shared__ u32 lh[4096];
    const int sel = blockIdx.y, b = sel >> 1, t = sel & 1;
    const int tid = threadIdx.x;
    for (int i = tid; i < 4096; i += 1024) lh[i] = 0;
    const float tbv = compute_sv_tb(boxes, scales, pdls, pdts, b, t, sv, red);
    const u32 p12 = meta[sel * MS + 0];
    const int e1 = min((int)(blockIdx.x + 1) * ECHUNK, NE);
    for (int e = blockIdx.x * ECHUNK + tid; e < e1; e += 1024) {
        u32 qb; QBITS(e, qb);
        if ((qb >> 20) == p12) atomicAdd(&lh[(qb >> 8) & 0xFFF], 1u);
    }
    __syncthreads();
    u32* G = gpart + ((size_t)sel * NCHUNK + blockIdx.x) * 4096;
    for (int i = tid; i < 4096; i += 1024) G[i] = lh[i];
}

// scanB: locate need1-th within p12 group -> prefix24, need2.
__global__ __launch_bounds__(1024) void scanB_kernel(
    const u32* __restrict__ gpart, u32* __restrict__ meta)
{
    const int sel = blockIdx.x, tid = threadIdx.x;
    const u32 TH = meta[sel * MS + 1];
    __shared__ u32 bins[4096];
    __shared__ u32 sc[2][1024];
    for (int b = tid; b < 4096; b += 1024) {
        u32 s = 0;
        for (int c = 0; c < NCHUNK; ++c) s += gpart[((size_t)sel * NCHUNK + c) * 4096 + b];
        bins[b] = s;
    }
    __syncthreads();
    u32 part = 0;
#pragma unroll
    for (int j = 0; j < 4; ++j) part += bins[tid * 4 + j];
    sc[0][tid] = part;
    __syncthreads();
    int src = 0;
    for (int st = 1; st < 1024; st <<= 1) {
        sc[1 - src][tid] = sc[src][tid] + (tid >= st ? sc[src][tid - st] : 0);
        __syncthreads(); src = 1 - src;
    }
    u32 inc = sc[src][tid], exc = inc - part;
    if (exc < TH && TH <= inc) {
        u32 cum = exc;
        for (int j = 0; j < 4; ++j) {
            u32 c = bins[tid * 4 + j];
            if (cum + c >= TH) {
                meta[sel * MS + 6] = (meta[sel * MS + 0] << 12) | (u32)(tid * 4 + j);
                meta[sel * MS + 7] = TH - cum;
                break;
            }
            cum += c;
        }
    }
}

// histC: among edges with top-24 == prefix24, LDS hist of low 8 bits.
__global__ __launch_bounds__(1024) void histC_kernel(
    const float* __restrict__ boxes, const float* __restrict__ scales,
    const float* __restrict__ pdls, const float* __restrict__ pdts,
    const u32* __restrict__ meta, u32* __restrict__ gpart)
{
    __shared__ float sv[512]; __shared__ float red[512];
    __shared__ u32 lh[256];
    const int sel = blockIdx.y, b = sel >> 1, t = sel & 1;
    const int tid = threadIdx.x;
    if (tid < 256) lh[tid] = 0;
    const float tbv = compute_sv_tb(boxes, scales, pdls, pdts, b, t, sv, red);
    const u32 p24 = meta[sel * MS + 6];
    const int e1 = min((int)(blockIdx.x + 1) * ECHUNK, NE);
    for (int e = blockIdx.x * ECHUNK + tid; e < e1; e += 1024) {
        u32 qb; QBITS(e, qb);
        if ((qb >> 8) == p24) atomicAdd(&lh[qb & 0xFF], 1u);
    }
    __syncthreads();
    u32* G = gpart + ((size_t)sel * NCHUNK + blockIdx.x) * 256;
    if (tid < 256) G[tid] = lh[tid];
}

// scanC: exact q*, then binary-search the w*-tie q-interval [qlo,qhi].
__global__ __launch_bounds__(256) void scanC_kernel(
    const u32* __restrict__ gpart, u32* __restrict__ meta)
{
    const int sel = blockIdx.x, tid = threadIdx.x;
    const u32 TH = meta[sel * MS + 7];
    __shared__ u32 bins[256];
    __shared__ u32 sc[2][256];
    __shared__ u32 s_qstar;
    u32 s = 0;
    for (int c = 0; c < NCHUNK; ++c) s += gpart[((size_t)sel * NCHUNK + c) * 256 + tid];
    bins[tid] = s;
    sc[0][tid] = s;
    __syncthreads();
    int src = 0;
    for (int st = 1; st < 256; st <<= 1) {
        sc[1 - src][tid] = sc[src][tid] + (tid >= st ? sc[src][tid - st] : 0);
        __syncthreads(); src = 1 - src;
    }
    u32 inc = sc[src][tid], exc = inc - bins[tid];
    if (exc < TH && TH <= inc)
        s_qstar = (meta[sel * MS + 6] << 8) | (u32)tid;
    __syncthreads();
    if (tid == 0) {
        u32 prefix = s_qstar;
        float qstar = __uint_as_float(prefix);
        float wstar = (float)exp(-(double)qstar);
        u32 lo = 0, hi = prefix;              // smallest qb with exp(-q)==w*
        while (lo < hi) {
            u32 mid = (lo + hi) >> 1;
            float wm = (float)exp(-(double)__uint_as_float(mid));
            if (wm > wstar) lo = mid + 1; else hi = mid;
        }
        meta[sel * MS + 2] = lo;
        lo = prefix; hi = 0x7F800000u;        // largest qb with exp(-q)==w*
        while (lo < hi) {
            u32 mid = (lo + hi + 1) >> 1;
            float wm = (float)exp(-(double)__uint_as_float(mid));
            if (wm < wstar) hi = mid - 1; else lo = mid;
        }
        meta[sel * MS + 3] = lo;
        meta[sel * MS + 4] = __float_as_uint(wstar);
    }
}

// ---------------------------------------------------------------------------
// emit: two-pass block-aggregated slot reservation. Winners -> es/ed/ewt;
// ties -> tiebuf.
// ---------------------------------------------------------------------------
__global__ __launch_bounds__(1024) void emit_kernel(
    const float* __restrict__ boxes, const float* __restrict__ scales,
    const float* __restrict__ pdls, const float* __restrict__ pdts,
    u32* __restrict__ meta, int* __restrict__ tiebuf, int* __restrict__ tiecnt,
    int* __restrict__ es, int* __restrict__ ed, float* __restrict__ ewt,
    int* __restrict__ indeg, float* __restrict__ degw)
{
    __shared__ float sv[512]; __shared__ float red[512];
    __shared__ int s_wcnt, s_tcnt, s_wbase, s_tbase;
    const int sel = blockIdx.y, b = sel >> 1, t = sel & 1;
    const int tid = threadIdx.x;
    const float tbv = compute_sv_tb(boxes, scales, pdls, pdts, b, t, sv, red);
    const u32 qlo = meta[sel * MS + 2], qhi = meta[sel * MS + 3];
    const int base = t * 16384 + b * 4096;
    const int e0 = blockIdx.x * ECHUNK + tid;
    const int e1 = min((int)(blockIdx.x + 1) * ECHUNK, NE);
    if (tid == 0) { s_wcnt = 0; s_tcnt = 0; }
    __syncthreads();
    int myw = 0, myt = 0;
    for (int e = e0; e < e1; e += 1024) {
        u32 qb; QBITS(e, qb);
        if (qb < qlo) ++myw;
        else if (qb <= qhi) ++myt;
    }
    if (myw) atomicAdd(&s_wcnt, myw);
    if (myt) atomicAdd(&s_tcnt, myt);
    __syncthreads();
    if (tid == 0) {
        s_wbase = (s_wcnt > 0) ? (int)atomicAdd(&meta[sel * MS + 5], (u32)s_wcnt) : 0;
        s_tbase = (s_tcnt > 0) ? atomicAdd(&tiecnt[sel * TS], s_tcnt) : 0;
        s_wcnt = 0; s_tcnt = 0;
    }
    __syncthreads();
    for (int e = e0; e < e1; e += 1024) {
        u32 qb; QBITS(e, qb);
        if (qb < qlo) {
            int i = e / 511; int jj = e - i * 511; int j = jj + (jj >= i ? 1 : 0);
            float wval = (float)exp(-(double)__uint_as_float(qb));
            int slot = s_wbase + atomicAdd(&s_wcnt, 1);
            es[base + slot] = b * 512 + i;
            ed[base + slot] = b * 512 + j;
            ewt[base + slot] = wval;
            atomicAdd(&indeg[t * 2048 + b * 512 + j], 1);
            atomicAdd(&degw[t * 2048 + b * 512 + j], wval);
        } else if (qb <= qhi) {
            int p = s_tbase + atomicAdd(&s_tcnt, 1);
            if (p < TIECAP) tiebuf[sel * TIECAP + p] = e;
        }
    }
}

// ---------------------------------------------------------------------------
// tie resolution (index-ascending, r = K - emitted) + indeg scan + dis.
// ---------------------------------------------------------------------------
__global__ __launch_bounds__(1024) void tie_scan_kernel(
    u32* __restrict__ meta, const int* __restrict__ tiebuf, const int* __restrict__ tiecnt,
    int* __restrict__ es, int* __restrict__ ed, float* __restrict__ ewt,
    int* __restrict__ indeg, float* __restrict__ degw,
    int* __restrict__ offs, float* __restrict__ dis)
{
    __shared__ int bufA[2048], bufB[2048];
    const int t = blockIdx.x, tid = threadIdx.x;
    for (int b = 0; b < 4; ++b) {
        int sel = b * 2 + t;
        int m = min(tiecnt[sel * TS], TIECAP);
        int r = KEDGE - (int)meta[sel * MS + 5];
        float wt = __uint_as_float(meta[sel * MS + 4]);
        int base = t * 16384 + b * 4096;
        for (int k = tid; k < m; k += 1024) {
            int e = tiebuf[sel * TIECAP + k];
            int rank = 0;
            for (int l = 0; l < m; ++l) rank += (tiebuf[sel * TIECAP + l] < e) ? 1 : 0;
            if (rank < r) {
                int i = e / 511; int jj = e - i * 511; int j = jj + (jj >= i ? 1 : 0);
                int slot = (int)atomicAdd(&meta[sel * MS + 5], 1u);
                es[base + slot] = b * 512 + i;
                ed[base + slot] = b * 512 + j;
                ewt[base + slot] = wt;
                atomicAdd(&indeg[t * 2048 + b * 512 + j], 1);
                atomicAdd(&degw[t * 2048 + b * 512 + j], wt);
            }
        }
    }
    __threadfence();
    __syncthreads();
    bufA[tid] = indeg[t * 2048 + tid];
    bufA[tid + 1024] = indeg[t * 2048 + tid + 1024];
    __syncthreads();
    int* src = bufA; int* dst = bufB;
    for (int st = 1; st < 2048; st <<= 1) {
        dst[tid] = src[tid] + (tid >= st ? src[tid - st] : 0);
        int k1 = tid + 1024;
        dst[k1] = src[k1] + (k1 >= st ? src[k1 - st] : 0);
        __syncthreads();
        int* tmp = src; src = dst; dst = tmp;
    }
    offs[t * 2048 + tid] = (tid == 0) ? 0 : src[tid - 1];
    offs[t * 2048 + tid + 1024] = src[tid + 1023];
    dis[t * 2048 + tid] = 1.0f / sqrtf(1.0f + degw[t * 2048 + tid]);
    dis[t * 2048 + tid + 1024] = 1.0f / sqrtf(1.0f + degw[t * 2048 + tid + 1024]);
}

// CSR fill
__global__ void fill_kernel(const int* __restrict__ ed, const int* __restrict__ offs,
                            int* __restrict__ fill, int* __restrict__ csr) {
    int idx = blockIdx.x * 256 + threadIdx.x;
    if (idx >= 32768) return;
    int t = idx >> 14, e = idx & 16383;
    int d = ed[t * 16384 + e] & 2047;
    int pos = offs[t * 2048 + d] + atomicAdd(&fill[t * 2048 + d], 1);
    csr[t * 16384 + pos] = e;
}

// E7: GCN aggregate -> feats f16
__global__ __launch_bounds__(256) void gcn_agg_kernel(
    const float* __restrict__ xw_row, const float* __restrict__ xw_col,
    const float* __restrict__ b_row, const float* __restrict__ b_col,
    const int* __restrict__ es, const float* __restrict__ ew,
    const int* __restrict__ csr, const int* __restrict__ offs,
    const int* __restrict__ indeg, const float* __restrict__ dis,
    _Float16* __restrict__ feat_row, _Float16* __restrict__ feat_col)
{
    int d = blockIdx.x; int t = blockIdx.y;
    const float* xw = t ? xw_col : xw_row;
    const float* bg = t ? b_col : b_row;
    _Float16* out = t ? feat_col : feat_row;
    int f0 = threadIdx.x, f1 = threadIdx.x + 256;
    float dd = dis[t * 2048 + d];
    float a0 = dd * dd * xw[(size_t)d * 512 + f0];
    float a1 = dd * dd * xw[(size_t)d * 512 + f1];
    int st = offs[t * 2048 + d], cnt = indeg[t * 2048 + d];
    for (int k = 0; k < cnt; ++k) {
        int e = csr[t * 16384 + st + k];
        int s = es[t * 16384 + e];
        float w = ew[t * 16384 + e];
        float coef = dis[t * 2048 + s] * w * dd;
        a0 += coef * xw[(size_t)s * 512 + f0];
        a1 += coef * xw[(size_t)s * 512 + f1];
    }
    a0 += bg[f0]; a1 += bg[f1];
    out[(size_t)d * 512 + f0] = (_Float16)fmaxf(a0, 0.f);
    out[(size_t)d * 512 + f1] = (_Float16)fmaxf(a1, 0.f);
}

// ---------------------------------------------------------------------------
extern "C" void kernel_launch(void* const* d_in, const int* in_sizes, int n_in,
                              void* d_out, int out_size, void* d_ws, size_t ws_size,
                              hipStream_t stream)
{
    const float* x      = (const float*)d_in[0];
    const float* boxes  = (const float*)d_in[1];
    const float* scales = (const float*)d_in[2];
    const float* pdls   = (const float*)d_in[3];
    const float* pdts   = (const float*)d_in[4];
    const float* W_dec  = (const float*)d_in[5];
    const float* b_dec  = (const float*)d_in[6];
    const float* W_box  = (const float*)d_in[7];
    const float* b_box  = (const float*)d_in[8];
    const float* W_cnn  = (const float*)d_in[9];
    const float* b_cnn  = (const float*)d_in[10];
    const float* W_grow = (const float*)d_in[11];
    const float* b_grow = (const float*)d_in[12];
    const float* W_gcol = (const float*)d_in[13];
    const float* b_gcol = (const float*)d_in[14];
    const float* W_rcls = (const float*)d_in[15];
    const float* b_rcls = (const float*)d_in[16];
    const float* W_ccls = (const float*)d_in[17];
    const float* b_ccls = (const float*)d_in[18];

    char* ws = (char*)d_ws;
    size_t off = 0;
    auto alloc = [&](size_t bytes) -> void* {
        void* p = ws + off;
        off = (off + bytes + 255) & ~(size_t)255;
        return p;
    };
    _Float16* xf16   = (_Float16*)alloc((size_t)4 * 2304 * 1024 * 2);  // NHWC in
    _Float16* wf16   = (_Float16*)alloc((size_t)256 * 9216 * 2);       // [o][tap][ch]
    _Float16* dec    = (_Float16*)alloc((size_t)4 * 2304 * 256 * 2);   // NHWC
    float*    pbuf   = (float*)   alloc((size_t)4 * PSLICE * 4);       // split-K(4) partials
    _Float16* cnn    = (_Float16*)alloc((size_t)2048 * 1024 * 2);
    _Float16* fusion = (_Float16*)alloc((size_t)2048 * 768 * 2);
    _Float16* WcT    = (_Float16*)alloc((size_t)512 * 1024 * 2);
    _Float16* WgrT   = (_Float16*)alloc((size_t)512 * 768 * 2);
    _Float16* WgcT   = (_Float16*)alloc((size_t)512 * 768 * 2);
    _Float16* WrT    = (_Float16*)alloc((size_t)228 * 512 * 2);
    _Float16* WccT   = (_Float16*)alloc((size_t)116 * 512 * 2);
    float* xw        = (float*)alloc((size_t)2097152 * 4);             // xw_row|xw_col
    _Float16* feats  = (_Float16*)alloc((size_t)2 * 2048 * 512 * 2);   // row|col
    int*  es     = (int*)  alloc((size_t)2 * 16384 * 4);
    int*  ed     = (int*)  alloc((size_t)2 * 16384 * 4);
    float* ewt   = (float*)alloc((size_t)2 * 16384 * 4);
    int*  offsA  = (int*)  alloc((size_t)4096 * 4);
    float* dis   = (float*)alloc((size_t)4096 * 4);
    int*  csr    = (int*)  alloc((size_t)2 * 16384 * 4);
    int*  tiebuf = (int*)  alloc((size_t)8 * TIECAP * 4);
    u32*  gpartA = (u32*)  alloc((size_t)8 * NCHUNK * 4096 * 4);   // fully overwritten
    u32*  gpartB = (u32*)  alloc((size_t)8 * NCHUNK * 4096 * 4);
    u32*  gpartC = (u32*)  alloc((size_t)8 * NCHUNK * 256 * 4);
    // ---- zero zone (one hipMemsetAsync) ----
    size_t z0 = off;
    u32*  meta   = (u32*)  alloc((size_t)8 * MS * 4);
    int*  tiecnt = (int*)  alloc((size_t)8 * TS * 4);
    int*  indeg  = (int*)  alloc((size_t)4096 * 4);
    float* degw  = (float*)alloc((size_t)4096 * 4);
    int*  fillA  = (int*)  alloc((size_t)4096 * 4);
    size_t z1 = off;

    float* out = (float*)d_out;

    hipMemsetAsync(ws + z0, 0, z1 - z0, stream);

    cvt_x_kernel<<<dim3(16, 48, 4), 256, 0, stream>>>(x, xf16);
    cvt_w_kernel<<<256, 256, 0, stream>>>(W_dec, wf16);
    conv_part_kernel<<<dim3(6, 8, 16), 256, 0, stream>>>(xf16, wf16, pbuf);
    conv_sum_kernel<<<2304, 256, 0, stream>>>(pbuf, b_dec, dec);
    roi_kernel<<<2048, 256, 0, stream>>>(dec, boxes, cnn);
    box_kernel<<<2048, 256, 0, stream>>>(boxes, W_box, b_box, fusion);
    // weight transposes (f16 [N][K])
    cvt_t_kernel<<<dim3(16, 32), 256, 0, stream>>>(W_cnn, WcT, 1024, 512);
    cvt_t_kernel<<<dim3(16, 24), 256, 0, stream>>>(W_grow, WgrT, 768, 512);
    cvt_t_kernel<<<dim3(16, 24), 256, 0, stream>>>(W_gcol, WgcT, 768, 512);
    cvt_t_kernel<<<dim3(8, 16), 256, 0, stream>>>(W_rcls, WrT, 512, 228);
    cvt_t_kernel<<<dim3(4, 16), 256, 0, stream>>>(W_ccls, WccT, 512, 116);
    // fusion[:,256:768] = relu(cnn @ W_cnn + b)
    gemm16_kernel<1, _Float16><<<dim3(8, 32), 256, 0, stream>>>(cnn, WcT, b_cnn, fusion + 256, 2048, 512, 1024, 768);
    // edge pipeline: 12+12+8 LDS-privatized radix select + emit + CSR
    histA_kernel<<<dim3(NCHUNK, 8), 1024, 0, stream>>>(boxes, scales, pdls, pdts, gpartA);
    scanA_kernel<<<8, 1024, 0, stream>>>(gpartA, meta);
    histB_kernel<<<dim3(NCHUNK, 8), 1024, 0, stream>>>(boxes, scales, pdls, pdts, meta, gpartB);
    scanB_kernel<<<8, 1024, 0, stream>>>(gpartB, meta);
    histC_kernel<<<dim3(NCHUNK, 8), 1024, 0, stream>>>(boxes, scales, pdls, pdts, meta, gpartC);
    scanC_kernel<<<8, 256, 0, stream>>>(gpartC, meta);
    emit_kernel<<<dim3(NCHUNK, 8), 1024, 0, stream>>>(boxes, scales, pdls, pdts, meta,
                                                      tiebuf, tiecnt, es, ed, ewt, indeg, degw);
    tie_scan_kernel<<<2, 1024, 0, stream>>>(meta, tiebuf, tiecnt, es, ed, ewt,
                                            indeg, degw, offsA, dis);
    fill_kernel<<<128, 256, 0, stream>>>(ed, offsA, fillA, csr);
    // xw = fusion @ W_g{row,col} (bias applied in aggregation) — one dual launch
    gemm16z_kernel<<<dim3(8, 32, 2), 256, 0, stream>>>(fusion, WgrT, WgcT, xw, xw + 1048576,
                                                       2048, 512, 768, 512);
    gcn_agg_kernel<<<dim3(2048, 2), 256, 0, stream>>>(xw, xw + 1048576, b_grow, b_gcol,
                                                      es, ewt, csr, offsA, indeg, dis,
                                                      feats, feats + (size_t)2048 * 512);
    // classifier heads (leaky 0.01) -> fp32 out
    gemm16_kernel<2, float><<<dim3(4, 32), 256, 0, stream>>>(feats, WrT, b_rcls, out, 2048, 228, 512, 228);
    gemm16_kernel<2, float><<<dim3(2, 32), 256, 0, stream>>>(feats + (size_t)2048 * 512, WccT, b_ccls,
                                                             out + (size_t)2048 * 228, 2048, 116, 512, 116);
}

// Round 15
// 369.958 us; speedup vs baseline: 1.1375x; 1.0298x over previous
//
#include <hip/hip_runtime.h>
#include <cstdint>
#include <math.h>

typedef unsigned int u32;
typedef unsigned long long u64;
typedef unsigned short ushort;

typedef __attribute__((ext_vector_type(8))) _Float16 f16x8;
typedef __attribute__((ext_vector_type(4))) _Float16 f16x4;
typedef __attribute__((ext_vector_type(4))) float f32x4;

#define NB    4
#define BnN   2048
#define NE    261632      // 512*511 ordered pairs per batch
#define NCHUNK 16
#define ECHUNK 16352      // NE/16
#define KEDGE 4096
#define TIECAP 2048
#define PSLICE 2359296    // 4*2304*256 elements per K-slice partial
#define MS    64          // meta stride (u32) per sel -> 256B, own cache lines
#define TS    64          // tiecnt stride (int) per sel

// meta[sel*MS+i]: 0:p12  1:need1  2:qlo  3:qhi  4:wstar  5:emitcnt  6:prefix24  7:need2
// ---------------------------------------------------------------------------
// convert input: NCHW fp32 -> NHWC f16.  grid (16 chgrp, 48 y, 4 b), block 256
// ---------------------------------------------------------------------------
__global__ __launch_bounds__(256) void cvt_x_kernel(
    const float* __restrict__ in, _Float16* __restrict__ xf)
{
    __shared__ _Float16 sh[64][49];
    int cg = blockIdx.x, y = blockIdx.y, b = blockIdx.z;
    int tid = threadIdx.x;
    for (int i = tid; i < 64 * 48; i += 256) {
        int cl = i / 48, x = i - cl * 48;
        sh[cl][x] = (_Float16)in[(((size_t)b * 1024 + cg * 64 + cl) * 48 + y) * 48 + x];
    }
    __syncthreads();
    for (int i = tid; i < 64 * 48; i += 256) {
        int x = i / 64, cl = i - x * 64;
        xf[((size_t)(b * 48 + y) * 48 + x) * 1024 + cg * 64 + cl] = sh[cl][x];
    }
}

// convert weights: [o][ch][3][3] fp32 -> [o][tap][ch] f16. grid 256, block 256
__global__ __launch_bounds__(256) void cvt_w_kernel(
    const float* __restrict__ W, _Float16* __restrict__ wf)
{
    __shared__ _Float16 sh[9216];
    int o = blockIdx.x, tid = threadIdx.x;
    for (int g = tid; g < 9216; g += 256)
        sh[g] = (_Float16)W[(size_t)o * 9216 + g];     // g = ch*9+tap
    __syncthreads();
    for (int g = tid; g < 9216; g += 256) {
        int tap = g >> 10, ch = g & 1023;
        wf[(size_t)o * 9216 + g] = sh[ch * 9 + tap];
    }
}

// ---------------------------------------------------------------------------
// fused transpose-convert of 5 weight matrices: fp32 [K][N] -> f16 [N][K].
// One launch; block picks its matrix from a tile-offset table.
// tiles per matrix: Wc 16x32=512, Wgr 16x24=384, Wgc 384, Wr 8x16=128, Wcc 4x16=64
// ---------------------------------------------------------------------------
__global__ __launch_bounds__(256) void cvt_t5_kernel(
    const float* __restrict__ Wc,  _Float16* __restrict__ WcT,
    const float* __restrict__ Wgr, _Float16* __restrict__ WgrT,
    const float* __restrict__ Wgc, _Float16* __restrict__ WgcT,
    const float* __restrict__ Wr,  _Float16* __restrict__ WrT,
    const float* __restrict__ Wcc, _Float16* __restrict__ WccT)
{
    __shared__ _Float16 sh[32][33];
    int bid = blockIdx.x;
    const float* in; _Float16* out; int K, N, tx0, ty0, ntx;
    if (bid < 512)       { in = Wc;  out = WcT;  K = 1024; N = 512; ntx = 16; bid -= 0;    }
    else if (bid < 896)  { in = Wgr; out = WgrT; K = 768;  N = 512; ntx = 16; bid -= 512;  }
    else if (bid < 1280) { in = Wgc; out = WgcT; K = 768;  N = 512; ntx = 16; bid -= 896;  }
    else if (bid < 1408) { in = Wr;  out = WrT;  K = 512;  N = 228; ntx = 8;  bid -= 1280; }
    else                 { in = Wcc; out = WccT; K = 512;  N = 116; ntx = 4;  bid -= 1408; }
    tx0 = (bid % ntx) * 32;   // n0
    ty0 = (bid / ntx) * 32;   // k0
    int tx = threadIdx.x & 31, ty = threadIdx.x >> 5;
#pragma unroll
    for (int i = 0; i < 4; ++i) {
        int k = ty0 + ty + i * 8, n = tx0 + tx;
        sh[ty + i * 8][tx] = (k < K && n < N) ? (_Float16)in[(size_t)k * N + n] : (_Float16)0.f;
    }
    __syncthreads();
#pragma unroll
    for (int i = 0; i < 4; ++i) {
        int n = tx0 + ty + i * 8, k = ty0 + tx;
        if (n < N && k < K) out[(size_t)n * K + k] = sh[tx][ty + i * 8];
    }
}

// ---------------------------------------------------------------------------
// conv 3x3 SAME 1024->256, split-K(4) partials. Implicit-GEMM MFMA f16.
// Block 256 thr (4 waves). Wave tile: 32 och x 2 rows x 48 px.
// LDS 50.4 KB -> 3 blocks/CU; grid (6,8,16) = 768 = exactly 3/CU, balanced.
// ---------------------------------------------------------------------------
__global__ __launch_bounds__(256) void conv_part_kernel(
    const _Float16* __restrict__ xf, const _Float16* __restrict__ wf,
    float* __restrict__ pbuf)
{
    __shared__ _Float16 wS[9][4][32][8];   // 18.4 KB  [tap][q][och32][8ch]
    __shared__ _Float16 xS[10][4][50][8];  // 32.0 KB  [row10][q][col][8ch]
    const int y0 = blockIdx.x * 8;
    const int og = blockIdx.y;             // 0..7 (32 och each)
    const int bz = blockIdx.z;
    const int b  = bz >> 2, ks = bz & 3;
    const int tid = threadIdx.x;
    const int wv = tid >> 6;
    const int ln = tid & 63;
    const int n  = ln & 15;
    const int q  = ln >> 4;

    f32x4 acc[2][2][3];
#pragma unroll
    for (int mt = 0; mt < 2; ++mt)
#pragma unroll
        for (int rr = 0; rr < 2; ++rr)
#pragma unroll
            for (int nt = 0; nt < 3; ++nt) acc[mt][rr][nt] = (f32x4){0.f, 0.f, 0.f, 0.f};

    const int c0 = ks * 256;
    for (int cc = c0; cc < c0 + 256; cc += 32) {
#pragma unroll
        for (int it = 0; it < 5; ++it) {
            int g = it * 256 + tid;
            if (g < 1152) {
                int tap = g >> 7, r = g & 127, qq = r >> 5, oc = r & 31;
                *(uint4*)&wS[tap][qq][oc][0] =
                    *(const uint4*)(wf + ((size_t)(og * 32 + oc) * 9 + tap) * 1024 + cc + qq * 8);
            }
        }
#pragma unroll
        for (int it = 0; it < 8; ++it) {
            int g = it * 256 + tid;
            if (g < 2000) {
                int row = g / 200, r2 = g - row * 200;
                int qq = r2 / 50, c = r2 - qq * 50;
                int gy = y0 + row - 1, gx = c - 1;
                uint4 v = make_uint4(0u, 0u, 0u, 0u);
                if ((unsigned)gy < 48u && (unsigned)gx < 48u)
                    v = *(const uint4*)(xf + ((size_t)(b * 48 + gy) * 48 + gx) * 1024 + cc + qq * 8);
                *(uint4*)&xS[row][qq][c][0] = v;
            }
        }
        __syncthreads();

#pragma unroll
        for (int tap = 0; tap < 9; ++tap) {
            const int dy = tap / 3, dx = tap % 3;
            f16x8 a0 = *(const f16x8*)&wS[tap][q][n][0];
            f16x8 a1 = *(const f16x8*)&wS[tap][q][16 + n][0];
#pragma unroll
            for (int rr = 0; rr < 2; ++rr) {
                const int row = 2 * wv + rr + dy;
#pragma unroll
                for (int nt = 0; nt < 3; ++nt) {
                    f16x8 bb = *(const f16x8*)&xS[row][q][nt * 16 + n + dx][0];
                    acc[0][rr][nt] = __builtin_amdgcn_mfma_f32_16x16x32_f16(a0, bb, acc[0][rr][nt], 0, 0, 0);
                    acc[1][rr][nt] = __builtin_amdgcn_mfma_f32_16x16x32_f16(a1, bb, acc[1][rr][nt], 0, 0, 0);
                }
            }
        }
        __syncthreads();
    }

#pragma unroll
    for (int rr = 0; rr < 2; ++rr) {
        const int y = y0 + 2 * wv + rr;
#pragma unroll
        for (int mt = 0; mt < 2; ++mt) {
#pragma unroll
            for (int nt = 0; nt < 3; ++nt) {
                int x = nt * 16 + n;
                *(f32x4*)(pbuf + (size_t)ks * PSLICE +
                          ((size_t)(b * 48 + y) * 48 + x) * 256 + og * 32 + mt * 16 + q * 4) = acc[mt][rr][nt];
            }
        }
    }
}

// sum 4 partials + bias + relu -> dec NHWC f16. grid 2304 x 256.
__global__ __launch_bounds__(256) void conv_sum_kernel(
    const float* __restrict__ pbuf, const float* __restrict__ bd,
    _Float16* __restrict__ dec)
{
    size_t idx = (size_t)blockIdx.x * 256 + threadIdx.x;   // 589824 threads
    size_t e = idx * 4;
    int och = (int)(e & 255);
    f32x4 s0 = *(const f32x4*)(pbuf + e);
    f32x4 s1 = *(const f32x4*)(pbuf + (size_t)PSLICE + e);
    f32x4 s2 = *(const f32x4*)(pbuf + (size_t)2 * PSLICE + e);
    f32x4 s3 = *(const f32x4*)(pbuf + (size_t)3 * PSLICE + e);
    float4 b4 = *(const float4*)(bd + och);
    f16x4 v;
    v.x = (_Float16)fmaxf(s0[0] + s1[0] + s2[0] + s3[0] + b4.x, 0.f);
    v.y = (_Float16)fmaxf(s0[1] + s1[1] + s2[1] + s3[1] + b4.y, 0.f);
    v.z = (_Float16)fmaxf(s0[2] + s1[2] + s2[2] + s3[2] + b4.z, 0.f);
    v.w = (_Float16)fmaxf(s0[3] + s1[3] + s2[3] + s3[3] + b4.w, 0.f);
    *(f16x4*)(dec + e) = v;
}

// ---------------------------------------------------------------------------
// ROI align 2x2 on NHWC f16 dec + fused box head.
// block n: thread c computes cnn[n][c*4..] (roi) AND fusion[n][c] (box head).
// ---------------------------------------------------------------------------
__global__ __launch_bounds__(256) void roi_box_kernel(
    const _Float16* __restrict__ dec, const float* __restrict__ boxes,
    const float* __restrict__ Wb, const float* __restrict__ bb,
    _Float16* __restrict__ cnn, _Float16* __restrict__ fusion)
{
    int n = blockIdx.x; int c = threadIdx.x;
    int b = n >> 9;
    float x1 = boxes[n * 4 + 0], y1 = boxes[n * 4 + 1];
    float x2 = boxes[n * 4 + 2], y2 = boxes[n * 4 + 3];
    // ---- box head ----
    {
        float bf0 = ((x1 + x2) * 0.5f) / 48.f;
        float bf1 = ((y1 + y2) * 0.5f) / 48.f;
        float bf2 = (x2 - x1) / 48.f;
        float bf3 = (y2 - y1) / 48.f;
        float acc = bb[c];
        acc += bf0 * Wb[0 * 256 + c];
        acc += bf1 * Wb[1 * 256 + c];
        acc += bf2 * Wb[2 * 256 + c];
        acc += bf3 * Wb[3 * 256 + c];
        fusion[(size_t)n * 768 + c] = (_Float16)fmaxf(acc, 0.f);
    }
    // ---- roi ----
    float bw = (x2 - x1) * 0.5f, bh = (y2 - y1) * 0.5f;
    float sxv[2] = { x1 + 0.5f * bw, x1 + 1.5f * bw };
    float syv[2] = { y1 + 0.5f * bh, y1 + 1.5f * bh };
    float px[4] = { sxv[0], sxv[1], sxv[0], sxv[1] };
    float py[4] = { syv[0], syv[0], syv[1], syv[1] };
    const _Float16* f = dec + (size_t)b * 2304 * 256;
    f16x4 o4;
    float res[4];
#pragma unroll
    for (int p = 0; p < 4; ++p) {
        float yy = fminf(fmaxf(py[p], 0.f), 47.f);
        float xx = fminf(fmaxf(px[p], 0.f), 47.f);
        int y0 = (int)floorf(yy), x0 = (int)floorf(xx);
        int y1i = min(y0 + 1, 47), x1i = min(x0 + 1, 47);
        float wy = yy - (float)y0, wx = xx - (float)x0;
        float f00 = (float)f[(size_t)(y0 * 48 + x0) * 256 + c];
        float f01 = (float)f[(size_t)(y0 * 48 + x1i) * 256 + c];
        float f10 = (float)f[(size_t)(y1i * 48 + x0) * 256 + c];
        float f11 = (float)f[(size_t)(y1i * 48 + x1i) * 256 + c];
        res[p] = f00 * (1.f - wy) * (1.f - wx) + f01 * (1.f - wy) * wx
               + f10 * wy * (1.f - wx) + f11 * wy * wx;
    }
    o4.x = (_Float16)res[0]; o4.y = (_Float16)res[1];
    o4.z = (_Float16)res[2]; o4.w = (_Float16)res[3];
    *(f16x4*)(cnn + (size_t)n * 1024 + c * 4) = o4;
}

// ---------------------------------------------------------------------------
// f16 MFMA GEMM: C = act(A @ Bt^T + bias). 64x64 tile, 4 waves 2x2.
// ---------------------------------------------------------------------------
template <int ACT, typename OUTT>
__global__ __launch_bounds__(256) void gemm16_kernel(
    const _Float16* __restrict__ A, const _Float16* __restrict__ Bt,
    const float* __restrict__ bias, OUTT* __restrict__ C,
    int M, int N, int K, int ldC)
{
    __shared__ _Float16 aS[64][4][8];
    __shared__ _Float16 bS[64][4][8];
    const int n0 = blockIdx.x * 64, m0 = blockIdx.y * 64;
    const int tid = threadIdx.x;
    const int wv = tid >> 6, ln = tid & 63;
    const int wm = wv & 1, wn = wv >> 1;
    const int lm = ln & 15, lq = ln >> 4;
    const int sr = tid >> 2, sq = tid & 3;

    f32x4 acc[2][2];
#pragma unroll
    for (int i = 0; i < 2; ++i)
#pragma unroll
        for (int j = 0; j < 2; ++j) acc[i][j] = (f32x4){0.f, 0.f, 0.f, 0.f};

    for (int cc = 0; cc < K; cc += 32) {
        *(uint4*)&aS[sr][sq][0] = *(const uint4*)(A + (size_t)(m0 + sr) * K + cc + sq * 8);
        uint4 bv = make_uint4(0u, 0u, 0u, 0u);
        if (n0 + sr < N)
            bv = *(const uint4*)(Bt + (size_t)(n0 + sr) * K + cc + sq * 8);
        *(uint4*)&bS[sr][sq][0] = bv;
        __syncthreads();
        f16x8 af[2], bf[2];
#pragma unroll
        for (int mt = 0; mt < 2; ++mt) af[mt] = *(const f16x8*)&aS[wm * 32 + mt * 16 + lm][lq][0];
#pragma unroll
        for (int nt = 0; nt < 2; ++nt) bf[nt] = *(const f16x8*)&bS[wn * 32 + nt * 16 + lm][lq][0];
#pragma unroll
        for (int mt = 0; mt < 2; ++mt)
#pragma unroll
            for (int nt = 0; nt < 2; ++nt)
                acc[mt][nt] = __builtin_amdgcn_mfma_f32_16x16x32_f16(af[mt], bf[nt], acc[mt][nt], 0, 0, 0);
        __syncthreads();
    }

#pragma unroll
    for (int mt = 0; mt < 2; ++mt) {
#pragma unroll
        for (int nt = 0; nt < 2; ++nt) {
            int col = n0 + wn * 32 + nt * 16 + lm;
            if (col >= N) continue;
            float bs = bias ? bias[col] : 0.f;
#pragma unroll
            for (int r = 0; r < 4; ++r) {
                int row = m0 + wm * 32 + mt * 16 + lq * 4 + r;
                float v = acc[mt][nt][r] + bs;
                if (ACT == 1) v = fmaxf(v, 0.f);
                if (ACT == 2) v = (v >= 0.f) ? v : 0.01f * v;
                C[(size_t)row * ldC + col] = (OUTT)v;
            }
        }
    }
}

// dual-B variant: grid.z selects (Bt, C). ACT=0, float out, no bias.
__global__ __launch_bounds__(256) void gemm16z_kernel(
    const _Float16* __restrict__ A,
    const _Float16* __restrict__ Bt0, const _Float16* __restrict__ Bt1,
    float* __restrict__ C0, float* __restrict__ C1,
    int M, int N, int K, int ldC)
{
    const _Float16* __restrict__ Bt = blockIdx.z ? Bt1 : Bt0;
    float* __restrict__ C = blockIdx.z ? C1 : C0;
    __shared__ _Float16 aS[64][4][8];
    __shared__ _Float16 bS[64][4][8];
    const int n0 = blockIdx.x * 64, m0 = blockIdx.y * 64;
    const int tid = threadIdx.x;
    const int wv = tid >> 6, ln = tid & 63;
    const int wm = wv & 1, wn = wv >> 1;
    const int lm = ln & 15, lq = ln >> 4;
    const int sr = tid >> 2, sq = tid & 3;

    f32x4 acc[2][2];
#pragma unroll
    for (int i = 0; i < 2; ++i)
#pragma unroll
        for (int j = 0; j < 2; ++j) acc[i][j] = (f32x4){0.f, 0.f, 0.f, 0.f};

    for (int cc = 0; cc < K; cc += 32) {
        *(uint4*)&aS[sr][sq][0] = *(const uint4*)(A + (size_t)(m0 + sr) * K + cc + sq * 8);
        uint4 bv = make_uint4(0u, 0u, 0u, 0u);
        if (n0 + sr < N)
            bv = *(const uint4*)(Bt + (size_t)(n0 + sr) * K + cc + sq * 8);
        *(uint4*)&bS[sr][sq][0] = bv;
        __syncthreads();
        f16x8 af[2], bf[2];
#pragma unroll
        for (int mt = 0; mt < 2; ++mt) af[mt] = *(const f16x8*)&aS[wm * 32 + mt * 16 + lm][lq][0];
#pragma unroll
        for (int nt = 0; nt < 2; ++nt) bf[nt] = *(const f16x8*)&bS[wn * 32 + nt * 16 + lm][lq][0];
#pragma unroll
        for (int mt = 0; mt < 2; ++mt)
#pragma unroll
            for (int nt = 0; nt < 2; ++nt)
                acc[mt][nt] = __builtin_amdgcn_mfma_f32_16x16x32_f16(af[mt], bf[nt], acc[mt][nt], 0, 0, 0);
        __syncthreads();
    }

#pragma unroll
    for (int mt = 0; mt < 2; ++mt) {
#pragma unroll
        for (int nt = 0; nt < 2; ++nt) {
            int col = n0 + wn * 32 + nt * 16 + lm;
            if (col >= N) continue;
#pragma unroll
            for (int r = 0; r < 4; ++r) {
                int row = m0 + wm * 32 + mt * 16 + lq * 4 + r;
                C[(size_t)row * ldC + col] = acc[mt][nt][r];
            }
        }
    }
}

// ---------------------------------------------------------------------------
// shared helper: per-sel centers sv[512] (LDS) + table extent tbv.
// ---------------------------------------------------------------------------
__device__ __forceinline__ float compute_sv_tb(
    const float* __restrict__ boxes, const float* __restrict__ scales,
    const float* __restrict__ pdls, const float* __restrict__ pdts,
    int b, int t, float* sv, float* red)
{
    int tid = threadIdx.x;
    float pdl = pdls[b], pdt = pdts[b], sc = scales[b];
    if (tid < 512) {
        const float* bx = boxes + (size_t)(b * 512 + tid) * 4;
        float o0 = (bx[0] - pdl) / sc;
        float o1 = (bx[1] - pdt) / sc;
        float o2 = (bx[2] - pdl) / sc;
        float o3 = (bx[3] - pdt) / sc;
        sv[tid]  = (t == 0) ? (o1 + o3) * 0.5f : (o0 + o2) * 0.5f;
        red[tid] = (t == 0) ? fmaxf(o1, o3)    : fmaxf(o0, o2);
    }
    __syncthreads();
    for (int s = 256; s > 0; s >>= 1) {
        if (tid < s) red[tid] = fmaxf(red[tid], red[tid + s]);
        __syncthreads();
    }
    float tbv = red[0];
    __syncthreads();
    return tbv;
}

#define QBITS(e, QB)                                                   \
    {                                                                  \
        int i_ = (e) / 511; int jj_ = (e) - i_ * 511;                  \
        int j_ = jj_ + (jj_ >= i_ ? 1 : 0);                            \
        float diff_ = sv[i_] - sv[j_];                                 \
        float u_ = (diff_ * 5.0f) / tbv;                               \
        float q_ = u_ * u_;                                            \
        QB = __float_as_uint(q_);                                      \
    }

// ---------------------------------------------------------------------------
// histA: LDS 4096-bin hist of top-12 q-bits, per-chunk partial.
// ---------------------------------------------------------------------------
__global__ __launch_bounds__(1024) void histA_kernel(
    const float* __restrict__ boxes, const float* __restrict__ scales,
    const float* __restrict__ pdls, const float* __restrict__ pdts,
    u32* __restrict__ gpart)
{
    __shared__ float sv[512]; __shared__ float red[512];
    __shared__ u32 lh[4096];
    const int sel = blockIdx.y, b = sel >> 1, t = sel & 1;
    const int tid = threadIdx.x;
    for (int i = tid; i < 4096; i += 1024) lh[i] = 0;
    const float tbv = compute_sv_tb(boxes, scales, pdls, pdts, b, t, sv, red);
    const int e1 = min((int)(blockIdx.x + 1) * ECHUNK, NE);
    for (int e = blockIdx.x * ECHUNK + tid; e < e1; e += 1024) {
        u32 qb; QBITS(e, qb);
        atomicAdd(&lh[qb >> 20], 1u);
    }
    __syncthreads();
    u32* G = gpart + ((size_t)sel * NCHUNK + blockIdx.x) * 4096;
    for (int i = tid; i < 4096; i += 1024) G[i] = lh[i];
}

// scanA
__global__ __launch_bounds__(1024) void scanA_kernel(
    const u32* __restrict__ gpart, u32* __restrict__ meta)
{
    const int sel = blockIdx.x, tid = threadIdx.x;
    __shared__ u32 bins[4096];
    __shared__ u32 sc[2][1024];
    for (int b = tid; b < 4096; b += 1024) {
        u32 s = 0;
        for (int c = 0; c < NCHUNK; ++c) s += gpart[((size_t)sel * NCHUNK + c) * 4096 + b];
        bins[b] = s;
    }
    __syncthreads();
    u32 part = 0;
#pragma unroll
    for (int j = 0; j < 4; ++j) part += bins[tid * 4 + j];
    sc[0][tid] = part;
    __syncthreads();
    int src = 0;
    for (int st = 1; st < 1024; st <<= 1) {
        sc[1 - src][tid] = sc[src][tid] + (tid >= st ? sc[src][tid - st] : 0);
        __syncthreads(); src = 1 - src;
    }
    u32 inc = sc[src][tid], exc = inc - part;
    if (exc < (u32)KEDGE && (u32)KEDGE <= inc) {
        u32 cum = exc;
        for (int j = 0; j < 4; ++j) {
            u32 c = bins[tid * 4 + j];
            if (cum + c >= (u32)KEDGE) {
                meta[sel * MS + 0] = (u32)(tid * 4 + j);
                meta[sel * MS + 1] = (u32)KEDGE - cum;
                break;
            }
            cum += c;
        }
    }
}

// histB: bits [19:8] among p12-matching edges.
__global__ __launch_bounds__(1024) void histB_kernel(
    const float* __restrict__ boxes, const float* __restrict__ scales,
    const float* __restrict__ pdls, const float* __restrict__ pdts,
    const u32* __restrict__ meta, u32* __restrict__ gpart)
{
    __shared__ float sv[512]; __shared__ float red[512];
    __shared__ u32 lh[4096];
    const int sel = blockIdx.y, b = sel >> 1, t = sel & 1;
    const int tid = threadIdx.x;
    for (int i = tid; i < 4096; i += 1024) lh[i] = 0;
    const float tbv = compute_sv_tb(boxes, scales, pdls, pdts, b, t, sv, red);
    const u32 p12 = meta[sel * MS + 0];
    const int e1 = min((int)(blockIdx.x + 1) * ECHUNK, NE);
    for (int e = blockIdx.x * ECHUNK + tid; e < e1; e += 1024) {
        u32 qb; QBITS(e, qb);
        if ((qb >> 20) == p12) atomicAdd(&lh[(qb >> 8) & 0xFFF], 1u);
    }
    __syncthreads();
    u32* G = gpart + ((size_t)sel * NCHUNK + blockIdx.x) * 4096;
    for (int i = tid; i < 4096; i += 1024) G[i] = lh[i];
}

// scanB
__global__ __launch_bounds__(1024) void scanB_kernel(
    const u32* __restrict__ gpart, u32* __restrict__ meta)
{
    const int sel = blockIdx.x, tid = threadIdx.x;
    const u32 TH = meta[sel * MS + 1];
    __shared__ u32 bins[4096];
    __shared__ u32 sc[2][1024];
    for (int b = tid; b < 4096; b += 1024) {
        u32 s = 0;
        for (int c = 0; c < NCHUNK; ++c) s += gpart[((size_t)sel * NCHUNK + c) * 4096 + b];
        bins[b] = s;
    }
    __syncthreads();
    u32 part = 0;
#pragma unroll
    for (int j = 0; j < 4; ++j) part += bins[tid * 4 + j];
    sc[0][tid] = part;
    __syncthreads();
    int src = 0;
    for (int st = 1; st < 1024; st <<= 1) {
        sc[1 - src][tid] = sc[src][tid] + (tid >= st ? sc[src][tid - st] : 0);
        __syncthreads(); src = 1 - src;
    }
    u32 inc = sc[src][tid], exc = inc - part;
    if (exc < TH && TH <= inc) {
        u32 cum = exc;
        for (int j = 0; j < 4; ++j) {
            u32 c = bins[tid * 4 + j];
            if (cum + c >= TH) {
                meta[sel * MS + 6] = (meta[sel * MS + 0] << 12) | (u32)(tid * 4 + j);
                meta[sel * MS + 7] = TH - cum;
                break;
            }
            cum += c;
        }
    }
}

// histC: low 8 bits among prefix24-matching edges.
__global__ __launch_bounds__(1024) void histC_kernel(
    const float* __restrict__ boxes, const float* __restrict__ scales,
    const float* __restrict__ pdls, const float* __restrict__ pdts,
    const u32* __restrict__ meta, u32* __restrict__ gpart)
{
    __shared__ float sv[512]; __shared__ float red[512];
    __shared__ u32 lh[256];
    const int sel = blockIdx.y, b = sel >> 1, t = sel & 1;
    const int tid = threadIdx.x;
    if (tid < 256) lh[tid] = 0;
    const float tbv = compute_sv_tb(boxes, scales, pdls, pdts, b, t, sv, red);
    const u32 p24 = meta[sel * MS + 6];
    const int e1 = min((int)(blockIdx.x + 1) * ECHUNK, NE);
    for (int e = blockIdx.x * ECHUNK + tid; e < e1; e += 1024) {
        u32 qb; QBITS(e, qb);
        if ((qb >> 8) == p24) atomicAdd(&lh[qb & 0xFF], 1u);
    }
    __syncthreads();
    u32* G = gpart + ((size_t)sel * NCHUNK + blockIdx.x) * 256;
    if (tid < 256) G[tid] = lh[tid];
}

// scanC: exact q*, then binary-search the w*-tie q-interval [qlo,qhi].
__global__ __launch_bounds__(256) void scanC_kernel(
    const u32* __restrict__ gpart, u32* __restrict__ meta)
{
    const int sel = blockIdx.x, tid = threadIdx.x;
    const u32 TH = meta[sel * MS + 7];
    __shared__ u32 bins[256];
    __shared__ u32 sc[2][256];
    __shared__ u32 s_qstar;
    u32 s = 0;
    for (int c = 0; c < NCHUNK; ++c) s += gpart[((size_t)sel * NCHUNK + c) * 256 + tid];
    bins[tid] = s;
    sc[0][tid] = s;
    __syncthreads();
    int src = 0;
    for (int st = 1; st < 256; st <<= 1) {
        sc[1 - src][tid] = sc[src][tid] + (tid >= st ? sc[src][tid - st] : 0);
        __syncthreads(); src = 1 - src;
    }
    u32 inc = sc[src][tid], exc = inc - bins[tid];
    if (exc < TH && TH <= inc)
        s_qstar = (meta[sel * MS + 6] << 8) | (u32)tid;
    __syncthreads();
    if (tid == 0) {
        u32 prefix = s_qstar;
        float qstar = __uint_as_float(prefix);
        float wstar = (float)exp(-(double)qstar);
        u32 lo = 0, hi = prefix;              // smallest qb with exp(-q)==w*
        while (lo < hi) {
            u32 mid = (lo + hi) >> 1;
            float wm = (float)exp(-(double)__uint_as_float(mid));
            if (wm > wstar) lo = mid + 1; else hi = mid;
        }
        meta[sel * MS + 2] = lo;
        lo = prefix; hi = 0x7F800000u;        // largest qb with exp(-q)==w*
        while (lo < hi) {
            u32 mid = (lo + hi + 1) >> 1;
            float wm = (float)exp(-(double)__uint_as_float(mid));
            if (wm < wstar) hi = mid - 1; else lo = mid;
        }
        meta[sel * MS + 3] = lo;
        meta[sel * MS + 4] = __float_as_uint(wstar);
    }
}

// ---------------------------------------------------------------------------
// emit: two-pass block-aggregated slot reservation.
// ---------------------------------------------------------------------------
__global__ __launch_bounds__(1024) void emit_kernel(
    const float* __restrict__ boxes, const float* __restrict__ scales,
    const float* __restrict__ pdls, const float* __restrict__ pdts,
    u32* __restrict__ meta, int* __restrict__ tiebuf, int* __restrict__ tiecnt,
    int* __restrict__ es, int* __restrict__ ed, float* __restrict__ ewt,
    int* __restrict__ indeg, float* __restrict__ degw)
{
    __shared__ float sv[512]; __shared__ float red[512];
    __shared__ int s_wcnt, s_tcnt, s_wbase, s_tbase;
    const int sel = blockIdx.y, b = sel >> 1, t = sel & 1;
    const int tid = threadIdx.x;
    const float tbv = compute_sv_tb(boxes, scales, pdls, pdts, b, t, sv, red);
    const u32 qlo = meta[sel * MS + 2], qhi = meta[sel * MS + 3];
    const int base = t * 16384 + b * 4096;
    const int e0 = blockIdx.x * ECHUNK + tid;
    const int e1 = min((int)(blockIdx.x + 1) * ECHUNK, NE);
    if (tid == 0) { s_wcnt = 0; s_tcnt = 0; }
    __syncthreads();
    int myw = 0, myt = 0;
    for (int e = e0; e < e1; e += 1024) {
        u32 qb; QBITS(e, qb);
        if (qb < qlo) ++myw;
        else if (qb <= qhi) ++myt;
    }
    if (myw) atomicAdd(&s_wcnt, myw);
    if (myt) atomicAdd(&s_tcnt, myt);
    __syncthreads();
    if (tid == 0) {
        s_wbase = (s_wcnt > 0) ? (int)atomicAdd(&meta[sel * MS + 5], (u32)s_wcnt) : 0;
        s_tbase = (s_tcnt > 0) ? atomicAdd(&tiecnt[sel * TS], s_tcnt) : 0;
        s_wcnt = 0; s_tcnt = 0;
    }
    __syncthreads();
    for (int e = e0; e < e1; e += 1024) {
        u32 qb; QBITS(e, qb);
        if (qb < qlo) {
            int i = e / 511; int jj = e - i * 511; int j = jj + (jj >= i ? 1 : 0);
            float wval = (float)exp(-(double)__uint_as_float(qb));
            int slot = s_wbase + atomicAdd(&s_wcnt, 1);
            es[base + slot] = b * 512 + i;
            ed[base + slot] = b * 512 + j;
            ewt[base + slot] = wval;
            atomicAdd(&indeg[t * 2048 + b * 512 + j], 1);
            atomicAdd(&degw[t * 2048 + b * 512 + j], wval);
        } else if (qb <= qhi) {
            int p = s_tbase + atomicAdd(&s_tcnt, 1);
            if (p < TIECAP) tiebuf[sel * TIECAP + p] = e;
        }
    }
}

// ---------------------------------------------------------------------------
// tie resolution + indeg scan + dis + CSR fill (fused; fill_kernel removed).
// grid 2 (t), block 1024.
// ---------------------------------------------------------------------------
__global__ __launch_bounds__(1024) void tie_scan_fill_kernel(
    u32* __restrict__ meta, const int* __restrict__ tiebuf, const int* __restrict__ tiecnt,
    int* __restrict__ es, int* __restrict__ ed, float* __restrict__ ewt,
    int* __restrict__ indeg, float* __restrict__ degw,
    int* __restrict__ offs, float* __restrict__ dis, int* __restrict__ csr)
{
    __shared__ int bufA[2048], bufB[2048];
    __shared__ int fill_l[2048];
    const int t = blockIdx.x, tid = threadIdx.x;
    for (int b = 0; b < 4; ++b) {
        int sel = b * 2 + t;
        int m = min(tiecnt[sel * TS], TIECAP);
        int r = KEDGE - (int)meta[sel * MS + 5];
        float wt = __uint_as_float(meta[sel * MS + 4]);
        int base = t * 16384 + b * 4096;
        for (int k = tid; k < m; k += 1024) {
            int e = tiebuf[sel * TIECAP + k];
            int rank = 0;
            for (int l = 0; l < m; ++l) rank += (tiebuf[sel * TIECAP + l] < e) ? 1 : 0;
            if (rank < r) {
                int i = e / 511; int jj = e - i * 511; int j = jj + (jj >= i ? 1 : 0);
                int slot = (int)atomicAdd(&meta[sel * MS + 5], 1u);
                es[base + slot] = b * 512 + i;
                ed[base + slot] = b * 512 + j;
                ewt[base + slot] = wt;
                atomicAdd(&indeg[t * 2048 + b * 512 + j], 1);
                atomicAdd(&degw[t * 2048 + b * 512 + j], wt);
            }
        }
    }
    __threadfence();
    __syncthreads();
    // exclusive scan of indeg -> offs (global + LDS copy in bufA)
    bufA[tid] = indeg[t * 2048 + tid];
    bufA[tid + 1024] = indeg[t * 2048 + tid + 1024];
    fill_l[tid] = 0; fill_l[tid + 1024] = 0;
    __syncthreads();
    int* src = bufA; int* dst = bufB;
    for (int st = 1; st < 2048; st <<= 1) {
        dst[tid] = src[tid] + (tid >= st ? src[tid - st] : 0);
        int k1 = tid + 1024;
        dst[k1] = src[k1] + (k1 >= st ? src[k1 - st] : 0);
        __syncthreads();
        int* tmp = src; src = dst; dst = tmp;
    }
    int off0 = (tid == 0) ? 0 : src[tid - 1];
    int off1 = src[tid + 1023];
    __syncthreads();
    // write offs to LDS (reuse dst buffer) + global
    dst[tid] = off0; dst[tid + 1024] = off1;
    offs[t * 2048 + tid] = off0;
    offs[t * 2048 + tid + 1024] = off1;
    dis[t * 2048 + tid] = 1.0f / sqrtf(1.0f + degw[t * 2048 + tid]);
    dis[t * 2048 + tid + 1024] = 1.0f / sqrtf(1.0f + degw[t * 2048 + tid + 1024]);
    __syncthreads();
    // CSR fill over this t's 16384 edges
    for (int e = tid; e < 16384; e += 1024) {
        int dl = ed[t * 16384 + e] & 2047;
        int pos = dst[dl] + atomicAdd(&fill_l[dl], 1);
        csr[t * 16384 + pos] = e;
    }
}

// E7: GCN aggregate -> feats f16
__global__ __launch_bounds__(256) void gcn_agg_kernel(
    const float* __restrict__ xw_row, const float* __restrict__ xw_col,
    const float* __restrict__ b_row, const float* __restrict__ b_col,
    const int* __restrict__ es, const float* __restrict__ ew,
    const int* __restrict__ csr, const int* __restrict__ offs,
    const int* __restrict__ indeg, const float* __restrict__ dis,
    _Float16* __restrict__ feat_row, _Float16* __restrict__ feat_col)
{
    int d = blockIdx.x; int t = blockIdx.y;
    const float* xw = t ? xw_col : xw_row;
    const float* bg = t ? b_col : b_row;
    _Float16* out = t ? feat_col : feat_row;
    int f0 = threadIdx.x, f1 = threadIdx.x + 256;
    float dd = dis[t * 2048 + d];
    float a0 = dd * dd * xw[(size_t)d * 512 + f0];
    float a1 = dd * dd * xw[(size_t)d * 512 + f1];
    int st = offs[t * 2048 + d], cnt = indeg[t * 2048 + d];
    for (int k = 0; k < cnt; ++k) {
        int e = csr[t * 16384 + st + k];
        int s = es[t * 16384 + e];
        float w = ew[t * 16384 + e];
        float coef = dis[t * 2048 + s] * w * dd;
        a0 += coef * xw[(size_t)s * 512 + f0];
        a1 += coef * xw[(size_t)s * 512 + f1];
    }
    a0 += bg[f0]; a1 += bg[f1];
    out[(size_t)d * 512 + f0] = (_Float16)fmaxf(a0, 0.f);
    out[(size_t)d * 512 + f1] = (_Float16)fmaxf(a1, 0.f);
}

// ---------------------------------------------------------------------------
extern "C" void kernel_launch(void* const* d_in, const int* in_sizes, int n_in,
                              void* d_out, int out_size, void* d_ws, size_t ws_size,
                              hipStream_t stream)
{
    const float* x      = (const float*)d_in[0];
    const float* boxes  = (const float*)d_in[1];
    const float* scales = (const float*)d_in[2];
    const float* pdls   = (const float*)d_in[3];
    const float* pdts   = (const float*)d_in[4];
    const float* W_dec  = (const float*)d_in[5];
    const float* b_dec  = (const float*)d_in[6];
    const float* W_box  = (const float*)d_in[7];
    const float* b_box  = (const float*)d_in[8];
    const float* W_cnn  = (const float*)d_in[9];
    const float* b_cnn  = (const float*)d_in[10];
    const float* W_grow = (const float*)d_in[11];
    const float* b_grow = (const float*)d_in[12];
    const float* W_gcol = (const float*)d_in[13];
    const float* b_gcol = (const float*)d_in[14];
    const float* W_rcls = (const float*)d_in[15];
    const float* b_rcls = (const float*)d_in[16];
    const float* W_ccls = (const float*)d_in[17];
    const float* b_ccls = (const float*)d_in[18];

    char* ws = (char*)d_ws;
    size_t off = 0;
    auto alloc = [&](size_t bytes) -> void* {
        void* p = ws + off;
        off = (off + bytes + 255) & ~(size_t)255;
        return p;
    };
    _Float16* xf16   = (_Float16*)alloc((size_t)4 * 2304 * 1024 * 2);  // NHWC in
    _Float16* wf16   = (_Float16*)alloc((size_t)256 * 9216 * 2);       // [o][tap][ch]
    _Float16* dec    = (_Float16*)alloc((size_t)4 * 2304 * 256 * 2);   // NHWC
    float*    pbuf   = (float*)   alloc((size_t)4 * PSLICE * 4);       // split-K(4) partials
    _Float16* cnn    = (_Float16*)alloc((size_t)2048 * 1024 * 2);
    _Float16* fusion = (_Float16*)alloc((size_t)2048 * 768 * 2);
    _Float16* WcT    = (_Float16*)alloc((size_t)512 * 1024 * 2);
    _Float16* WgrT   = (_Float16*)alloc((size_t)512 * 768 * 2);
    _Float16* WgcT   = (_Float16*)alloc((size_t)512 * 768 * 2);
    _Float16* WrT    = (_Float16*)alloc((size_t)228 * 512 * 2);
    _Float16* WccT   = (_Float16*)alloc((size_t)116 * 512 * 2);
    float* xw        = (float*)alloc((size_t)2097152 * 4);             // xw_row|xw_col
    _Float16* feats  = (_Float16*)alloc((size_t)2 * 2048 * 512 * 2);   // row|col
    int*  es     = (int*)  alloc((size_t)2 * 16384 * 4);
    int*  ed     = (int*)  alloc((size_t)2 * 16384 * 4);
    float* ewt   = (float*)alloc((size_t)2 * 16384 * 4);
    int*  offsA  = (int*)  alloc((size_t)4096 * 4);
    float* dis   = (float*)alloc((size_t)4096 * 4);
    int*  csr    = (int*)  alloc((size_t)2 * 16384 * 4);
    int*  tiebuf = (int*)  alloc((size_t)8 * TIECAP * 4);
    u32*  gpartA = (u32*)  alloc((size_t)8 * NCHUNK * 4096 * 4);   // fully overwritten
    u32*  gpartB = (u32*)  alloc((size_t)8 * NCHUNK * 4096 * 4);
    u32*  gpartC = (u32*)  alloc((size_t)8 * NCHUNK * 256 * 4);
    // ---- zero zone (one hipMemsetAsync) ----
    size_t z0 = off;
    u32*  meta   = (u32*)  alloc((size_t)8 * MS * 4);
    int*  tiecnt = (int*)  alloc((size_t)8 * TS * 4);
    int*  indeg  = (int*)  alloc((size_t)4096 * 4);
    float* degw  = (float*)alloc((size_t)4096 * 4);
    size_t z1 = off;

    float* out = (float*)d_out;

    hipMemsetAsync(ws + z0, 0, z1 - z0, stream);

    cvt_x_kernel<<<dim3(16, 48, 4), 256, 0, stream>>>(x, xf16);
    cvt_w_kernel<<<256, 256, 0, stream>>>(W_dec, wf16);
    conv_part_kernel<<<dim3(6, 8, 16), 256, 0, stream>>>(xf16, wf16, pbuf);
    conv_sum_kernel<<<2304, 256, 0, stream>>>(pbuf, b_dec, dec);
    roi_box_kernel<<<2048, 256, 0, stream>>>(dec, boxes, W_box, b_box, cnn, fusion);
    // all 5 weight transposes in one launch
    cvt_t5_kernel<<<1472, 256, 0, stream>>>(W_cnn, WcT, W_grow, WgrT, W_gcol, WgcT,
                                            W_rcls, WrT, W_ccls, WccT);
    // fusion[:,256:768] = relu(cnn @ W_cnn + b)
    gemm16_kernel<1, _Float16><<<dim3(8, 32), 256, 0, stream>>>(cnn, WcT, b_cnn, fusion + 256, 2048, 512, 1024, 768);
    // edge pipeline: 12+12+8 LDS-privatized radix select + emit + CSR
    histA_kernel<<<dim3(NCHUNK, 8), 1024, 0, stream>>>(boxes, scales, pdls, pdts, gpartA);
    scanA_kernel<<<8, 1024, 0, stream>>>(gpartA, meta);
    histB_kernel<<<dim3(NCHUNK, 8), 1024, 0, stream>>>(boxes, scales, pdls, pdts, meta, gpartB);
    scanB_kernel<<<8, 1024, 0, stream>>>(gpartB, meta);
    histC_kernel<<<dim3(NCHUNK, 8), 1024, 0, stream>>>(boxes, scales, pdls, pdts, meta, gpartC);
    scanC_kernel<<<8, 256, 0, stream>>>(gpartC, meta);
    emit_kernel<<<dim3(NCHUNK, 8), 1024, 0, stream>>>(boxes, scales, pdls, pdts, meta,
                                                      tiebuf, tiecnt, es, ed, ewt, indeg, degw);
    tie_scan_fill_kernel<<<2, 1024, 0, stream>>>(meta, tiebuf, tiecnt, es, ed, ewt,
                                                 indeg, degw, offsA, dis, csr);
    // xw = fusion @ W_g{row,col} (bias applied in aggregation) — one dual launch
    gemm16z_kernel<<<dim3(8, 32, 2), 256, 0, stream>>>(fusion, WgrT, WgcT, xw, xw + 1048576,
                                                       2048, 512, 768, 512);
    gcn_agg_kernel<<<dim3(2048, 2), 256, 0, stream>>>(xw, xw + 1048576, b_grow, b_gcol,
                                                      es, ewt, csr, offsA, indeg, dis,
                                                      feats, feats + (size_t)2048 * 512);
    // classifier heads (leaky 0.01) -> fp32 out
    gemm16_kernel<2, float><<<dim3(4, 32), 256, 0, stream>>>(feats, WrT, b_rcls, out, 2048, 228, 512, 228);
    gemm16_kernel<2, float><<<dim3(2, 32), 256, 0, stream>>>(feats + (size_t)2048 * 512, WccT, b_ccls,
                                                             out + (size_t)2048 * 228, 2048, 116, 512, 116);
}